// Round 12
// baseline (236.951 us; speedup 1.0000x reference)
//
#include <hip/hip_runtime.h>
#include <hip/hip_bf16.h>

#define B_ 4
#define N_ 10000
#define E_ 160000
#define D_ 128
#define H_ 4
#define HID_ 128
#define DK_ 32
#define DE_ 16

typedef __attribute__((ext_vector_type(8))) short short8v;
typedef __attribute__((ext_vector_type(4))) short short4v;
typedef __attribute__((ext_vector_type(4))) float f32x4;
typedef __attribute__((ext_vector_type(2))) float f32x2;

// fp32 -> bf16 bits, round-to-nearest-even
__device__ __forceinline__ short bfb(float f) {
  union { float f; unsigned u; } c; c.f = f;
  unsigned u = c.u + 0x7FFFu + ((c.u >> 16) & 1u);
  return (short)(u >> 16);
}

// fp32 -> fp8 e4m3 (OCP on gfx950)
__device__ __forceinline__ unsigned char f2fp8(float f) {
  int r = __builtin_amdgcn_cvt_pk_fp8_f32(f, f, 0, false);
  return (unsigned char)(r & 0xff);
}
// 2 packed fp8 -> 2 fp32
__device__ __forceinline__ f32x2 fp8x2f(unsigned short u) {
  return __builtin_amdgcn_cvt_pk_f32_fp8((int)u, false);
}

// ---------------------------------------------------------------------------
// P0: W^T bf16 prep. wt[m][n][k] = bf16(W_m[k*128+n]),  m: 0=q 1=k 2=v 3=o
// ---------------------------------------------------------------------------
__global__ __launch_bounds__(256) void wt_prep(
    const float* __restrict__ Wq, const float* __restrict__ Wk,
    const float* __restrict__ Wv, const float* __restrict__ Wo,
    short* __restrict__ wt) {
  const float* Ws[4] = {Wq, Wk, Wv, Wo};
  const int i = blockIdx.x * 256 + threadIdx.x;   // 0..65535
  const int m = i >> 14;
  const int k = (i >> 7) & 127;
  const int n = i & 127;
  wt[(size_t)m * 16384 + n * 128 + k] = bfb(Ws[m][k * 128 + n]);
}

// ---------------------------------------------------------------------------
// K1: QKV projection via MFMA. block = 256 (4 waves), 64 rows/block.
// Q -> fp32 [b][n][128]; K,V -> fp8 e4m3 kv8[n][b][0:128 = K | 128:256 = V]
// ---------------------------------------------------------------------------
__global__ __launch_bounds__(256) void qkv_mfma(
    const float* __restrict__ x, const short* __restrict__ wt,
    const float* __restrict__ bq, const float* __restrict__ bk,
    const float* __restrict__ bv,
    float* __restrict__ Q, unsigned char* __restrict__ kv8) {
  __shared__ short xs[64][136];
  const int tid  = threadIdx.x;
  const int lane = tid & 63;
  const int wave = tid >> 6;
  const int ln15 = lane & 15;
  const int g    = lane >> 4;
  const long rowBase = (long)blockIdx.x * 64;

  for (int i = tid; i < 64 * 32; i += 256) {
    const int r  = i >> 5;
    const int c4 = (i & 31) * 4;
    const float4 v = *(const float4*)(x + (rowBase + r) * 128 + c4);
    short4v sv; sv.x = bfb(v.x); sv.y = bfb(v.y); sv.z = bfb(v.z); sv.w = bfb(v.w);
    *(short4v*)&xs[r][c4] = sv;
  }
  __syncthreads();

  short8v af[4];
#pragma unroll
  for (int kk = 0; kk < 4; ++kk)
    af[kk] = *(const short8v*)&xs[wave * 16 + ln15][kk * 32 + g * 8];

  const float* bs[3] = {bq, bk, bv};

  int bbv[4], nnv[4];
#pragma unroll
  for (int r = 0; r < 4; ++r) {
    const long row = rowBase + wave * 16 + g * 4 + r;
    bbv[r] = (int)(row / N_);
    nnv[r] = (int)(row - (long)bbv[r] * N_);
  }

#pragma unroll
  for (int m = 0; m < 3; ++m) {
    const short* Wt = wt + (size_t)m * 16384;
    f32x4 acc[8];
#pragma unroll
    for (int cb = 0; cb < 8; ++cb) acc[cb] = (f32x4){0.f, 0.f, 0.f, 0.f};

#pragma unroll
    for (int kk = 0; kk < 4; ++kk) {
#pragma unroll
      for (int cb = 0; cb < 8; ++cb) {
        const short8v bfr =
            *(const short8v*)(Wt + (cb * 16 + ln15) * 128 + kk * 32 + g * 8);
        acc[cb] = __builtin_amdgcn_mfma_f32_16x16x32_bf16(af[kk], bfr, acc[cb], 0, 0, 0);
      }
    }

    const float* bias = bs[m];
#pragma unroll
    for (int cb = 0; cb < 8; ++cb) {
      const int col = cb * 16 + ln15;
      const float bv_ = bias[col];
#pragma unroll
      for (int r = 0; r < 4; ++r) {
        const float val = acc[cb][r] + bv_;
        if (m == 0) {
          const long row = rowBase + wave * 16 + g * 4 + r;
          Q[row * 128 + col] = val;
        } else {
          kv8[(((size_t)nnv[r] * 4 + bbv[r]) << 8) + (m - 1) * 128 + col] = f2fp8(val);
        }
      }
    }
  }
}

// ---------------------------------------------------------------------------
// CSR build
// ---------------------------------------------------------------------------
__global__ __launch_bounds__(256) void csr_hist(const int* __restrict__ ei,
                                                int* __restrict__ cnt) {
  const int e = blockIdx.x * 256 + threadIdx.x;
  if (e < E_) atomicAdd(&cnt[ei[E_ + e]], 1);
}

__global__ __launch_bounds__(1024) void csr_scan(const int* __restrict__ cnt,
                                                 int* __restrict__ rowptr,
                                                 int* __restrict__ fill) {
  __shared__ int part[1024];
  const int t = threadIdx.x;
  int local[10];
  int sum = 0;
#pragma unroll
  for (int i = 0; i < 10; ++i) {
    const int idx = t * 10 + i;
    local[i] = sum;
    sum += (idx < N_) ? cnt[idx] : 0;
  }
  part[t] = sum;
  __syncthreads();
  for (int off = 1; off < 1024; off <<= 1) {
    const int v = (t >= off) ? part[t - off] : 0;
    __syncthreads();
    part[t] += v;
    __syncthreads();
  }
  const int excl = (t == 0) ? 0 : part[t - 1];
#pragma unroll
  for (int i = 0; i < 10; ++i) {
    const int idx = t * 10 + i;
    if (idx <= N_) {
      const int o = excl + local[i];
      rowptr[idx] = o;
      if (idx < N_) fill[idx] = o;
    }
  }
}

// scatter: CSR-ordered src + CSR-ordered copy of edge_attr
__global__ __launch_bounds__(256) void csr_scatter(
    const int* __restrict__ ei, const float* __restrict__ ea,
    int* __restrict__ fill, int* __restrict__ esrc, float* __restrict__ eas) {
  const int e = blockIdx.x * 256 + threadIdx.x;
  if (e < E_) {
    const int dst = ei[E_ + e];
    const int pos = atomicAdd(&fill[dst], 1);
    esrc[pos] = ei[e];
    const float4* s4 = (const float4*)(ea + (size_t)e * 16);
    float4* d4 = (float4*)(eas + (size_t)pos * 16);
    d4[0] = s4[0]; d4[1] = s4[1]; d4[2] = s4[2]; d4[3] = s4[3];
  }
}

// ---------------------------------------------------------------------------
// K2: fused FiLM + logits + softmax + aggregation.  (R9 base, restructured)
// block per node; wave = head h; lane = 4*p + b  (p = dim-pair 0..15, b = batch).
// Stage-interleaved unroll-4: all 4 edges advance through each phase together
// so the 4 independent shuffle chains pipeline instead of serializing.
// FiLM: lane computes 8 j-rows (split by b&1) -> ONE shfl_xor(1) level.
// Logit reduce over p-lanes: shfl_xor(4,8,16,32), interleaved by level.
// Masked pad-4 (no serial remainder). Single-pass softmax (no max).
// ---------------------------------------------------------------------------
__global__ __launch_bounds__(256) void fused_attn(
    const int* __restrict__ rowptr, const int* __restrict__ esrc,
    const float* __restrict__ eas, const float* __restrict__ Wf,
    const float* __restrict__ bf, const float* __restrict__ Q,
    const unsigned char* __restrict__ kv8, float* __restrict__ agg) {
  const int node = blockIdx.x;
  const int h    = threadIdx.x >> 6;   // wave = head
  const int lane = threadIdx.x & 63;
  const int b    = lane & 3;           // batch
  const int p    = lane >> 2;          // dim-pair within head
  const int col0 = h * 32 + 2 * p;
  const int jb   = (b & 1) * 8;        // this lane's 8 j-rows

  // Wf slice: rows [jb, jb+8), gamma cols {col0,col0+1}, beta cols {128+col0,..}
  float2 wg[8], wb[8];
#pragma unroll
  for (int jj = 0; jj < 8; ++jj) {
    wg[jj] = *(const float2*)(Wf + (jb + jj) * 256 + col0);
    wb[jj] = *(const float2*)(Wf + (jb + jj) * 256 + 128 + col0);
  }
  const float bg0 = 1.f + bf[col0], bg1 = 1.f + bf[col0 + 1];
  const float bb0 = bf[128 + col0], bb1 = bf[129 + col0];

  const float2 q2 = *(const float2*)(Q + ((size_t)b * N_ + node) * 128 + col0);

  const int beg = rowptr[node], end = rowptr[node + 1];
  float acc0 = 0.f, acc1 = 0.f, se = 0.f;

  for (int i0 = beg; i0 < end; i0 += 4) {
    // ---- S0: index + batched loads (4 esrc, 4 eas x 32B, 8 kv ushort) ----
    int idx[4]; bool val[4];
#pragma unroll
    for (int u = 0; u < 4; ++u) {
      const int ii = i0 + u;
      val[u] = ii < end;
      idx[u] = val[u] ? ii : (end - 1);
    }
    int s[4];
#pragma unroll
    for (int u = 0; u < 4; ++u) s[u] = esrc[idx[u]];
    float4 ea0[4], ea1[4];
#pragma unroll
    for (int u = 0; u < 4; ++u) {
      const float* ep = eas + (size_t)idx[u] * 16 + jb;
      ea0[u] = *(const float4*)ep;
      ea1[u] = *(const float4*)(ep + 4);
    }
    unsigned short kk[4], vv[4];
#pragma unroll
    for (int u = 0; u < 4; ++u) {
      const unsigned char* kp = kv8 + ((((size_t)s[u] << 2) + b) << 8) + col0;
      kk[u] = *(const unsigned short*)kp;
      vv[u] = *(const unsigned short*)(kp + 128);
    }

    // ---- S1: FiLM partials, 8 j-rows per lane (32 FMA / edge) ----
    float g0[4], g1[4], t0[4], t1[4];
#pragma unroll
    for (int u = 0; u < 4; ++u) {
      const float e0 = ea0[u].x, e1 = ea0[u].y, e2 = ea0[u].z, e3 = ea0[u].w;
      const float e4 = ea1[u].x, e5 = ea1[u].y, e6 = ea1[u].z, e7 = ea1[u].w;
      float a0 = e0 * wg[0].x, a1 = e0 * wg[0].y;
      float c0 = e0 * wb[0].x, c1 = e0 * wb[0].y;
      a0 = fmaf(e1, wg[1].x, a0); a1 = fmaf(e1, wg[1].y, a1);
      c0 = fmaf(e1, wb[1].x, c0); c1 = fmaf(e1, wb[1].y, c1);
      a0 = fmaf(e2, wg[2].x, a0); a1 = fmaf(e2, wg[2].y, a1);
      c0 = fmaf(e2, wb[2].x, c0); c1 = fmaf(e2, wb[2].y, c1);
      a0 = fmaf(e3, wg[3].x, a0); a1 = fmaf(e3, wg[3].y, a1);
      c0 = fmaf(e3, wb[3].x, c0); c1 = fmaf(e3, wb[3].y, c1);
      a0 = fmaf(e4, wg[4].x, a0); a1 = fmaf(e4, wg[4].y, a1);
      c0 = fmaf(e4, wb[4].x, c0); c1 = fmaf(e4, wb[4].y, c1);
      a0 = fmaf(e5, wg[5].x, a0); a1 = fmaf(e5, wg[5].y, a1);
      c0 = fmaf(e5, wb[5].x, c0); c1 = fmaf(e5, wb[5].y, c1);
      a0 = fmaf(e6, wg[6].x, a0); a1 = fmaf(e6, wg[6].y, a1);
      c0 = fmaf(e6, wb[6].x, c0); c1 = fmaf(e6, wb[6].y, c1);
      a0 = fmaf(e7, wg[7].x, a0); a1 = fmaf(e7, wg[7].y, a1);
      c0 = fmaf(e7, wb[7].x, c0); c1 = fmaf(e7, wb[7].y, c1);
      g0[u] = a0; g1[u] = a1; t0[u] = c0; t1[u] = c1;
    }

    // ---- S2: one film shuffle level (16 independent shuffles) ----
#pragma unroll
    for (int u = 0; u < 4; ++u) g0[u] += __shfl_xor(g0[u], 1);
#pragma unroll
    for (int u = 0; u < 4; ++u) g1[u] += __shfl_xor(g1[u], 1);
#pragma unroll
    for (int u = 0; u < 4; ++u) t0[u] += __shfl_xor(t0[u], 1);
#pragma unroll
    for (int u = 0; u < 4; ++u) t1[u] += __shfl_xor(t1[u], 1);

    // ---- S3: bias + K-mod + logit partial ----
    float pl[4];
#pragma unroll
    for (int u = 0; u < 4; ++u) {
      const f32x2 kf = fp8x2f(kk[u]);
      const float km0 = fmaf(kf.x, g0[u] + bg0, t0[u] + bb0);
      const float km1 = fmaf(kf.y, g1[u] + bg1, t1[u] + bb1);
      pl[u] = fmaf(q2.x, km0, q2.y * km1);
    }

    // ---- S4: logit reduce over p-lanes, interleaved by level ----
#pragma unroll
    for (int u = 0; u < 4; ++u) pl[u] += __shfl_xor(pl[u], 4);
#pragma unroll
    for (int u = 0; u < 4; ++u) pl[u] += __shfl_xor(pl[u], 8);
#pragma unroll
    for (int u = 0; u < 4; ++u) pl[u] += __shfl_xor(pl[u], 16);
#pragma unroll
    for (int u = 0; u < 4; ++u) pl[u] += __shfl_xor(pl[u], 32);

    // ---- S5: exp + mask + accumulate ----
#pragma unroll
    for (int u = 0; u < 4; ++u) {
      float ex = __expf(pl[u] * 0.17677669529663687f);  // 1/sqrt(32)
      ex = val[u] ? ex : 0.f;
      const f32x2 vf = fp8x2f(vv[u]);
      se += ex;
      acc0 = fmaf(ex, vf.x, acc0);
      acc1 = fmaf(ex, vf.y, acc1);
    }
  }

  const float inv = (end > beg) ? 1.f / se : 0.f;
  float2 o; o.x = acc0 * inv; o.y = acc1 * inv;
  *(float2*)(agg + ((size_t)b * N_ + node) * 128 + col0) = o;
}

// ---------------------------------------------------------------------------
// K4: y = agg @ Wo + bo (MFMA); h = x + y; LayerNorm(h) -> out
// ---------------------------------------------------------------------------
__global__ __launch_bounds__(256) void out_ln_mfma(
    const float* __restrict__ agg, const short* __restrict__ wto,
    const float* __restrict__ bo, const float* __restrict__ x,
    const float* __restrict__ lng, const float* __restrict__ lnb,
    float* __restrict__ out) {
  __shared__ short as_[64][136];
  const int tid  = threadIdx.x;
  const int lane = tid & 63;
  const int wave = tid >> 6;
  const int ln15 = lane & 15;
  const int g    = lane >> 4;
  const long rowBase = (long)blockIdx.x * 64;

  for (int i = tid; i < 64 * 32; i += 256) {
    const int r  = i >> 5;
    const int c4 = (i & 31) * 4;
    const float4 v = *(const float4*)(agg + (rowBase + r) * 128 + c4);
    short4v sv; sv.x = bfb(v.x); sv.y = bfb(v.y); sv.z = bfb(v.z); sv.w = bfb(v.w);
    *(short4v*)&as_[r][c4] = sv;
  }
  __syncthreads();

  short8v af[4];
#pragma unroll
  for (int kk = 0; kk < 4; ++kk)
    af[kk] = *(const short8v*)&as_[wave * 16 + ln15][kk * 32 + g * 8];

  f32x4 acc[8];
#pragma unroll
  for (int cb = 0; cb < 8; ++cb) acc[cb] = (f32x4){0.f, 0.f, 0.f, 0.f};

#pragma unroll
  for (int kk = 0; kk < 4; ++kk) {
#pragma unroll
    for (int cb = 0; cb < 8; ++cb) {
      const short8v bfr =
          *(const short8v*)(wto + (cb * 16 + ln15) * 128 + kk * 32 + g * 8);
      acc[cb] = __builtin_amdgcn_mfma_f32_16x16x32_bf16(af[kk], bfr, acc[cb], 0, 0, 0);
    }
  }

#pragma unroll
  for (int cb = 0; cb < 8; ++cb) {
    const int col = cb * 16 + ln15;
    const float bov = bo[col];
#pragma unroll
    for (int r = 0; r < 4; ++r) {
      const long row = rowBase + wave * 16 + g * 4 + r;
      acc[cb][r] += bov + x[row * 128 + col];
    }
  }

  float s1[4], s2[4];
#pragma unroll
  for (int r = 0; r < 4; ++r) {
    s1[r] = 0.f; s2[r] = 0.f;
#pragma unroll
    for (int cb = 0; cb < 8; ++cb) {
      s1[r] += acc[cb][r];
      s2[r] = fmaf(acc[cb][r], acc[cb][r], s2[r]);
    }
  }
#pragma unroll
  for (int m = 1; m < 16; m <<= 1) {
#pragma unroll
    for (int r = 0; r < 4; ++r) {
      s1[r] += __shfl_xor(s1[r], m);
      s2[r] += __shfl_xor(s2[r], m);
    }
  }
  float mu[4], inv[4];
#pragma unroll
  for (int r = 0; r < 4; ++r) {
    mu[r] = s1[r] * (1.f / 128.f);
    const float var = s2[r] * (1.f / 128.f) - mu[r] * mu[r];
    inv[r] = rsqrtf(var + 1e-5f);
  }

#pragma unroll
  for (int cb = 0; cb < 8; ++cb) {
    const int col = cb * 16 + ln15;
    const float gv = lng[col], bv_ = lnb[col];
#pragma unroll
    for (int r = 0; r < 4; ++r) {
      const long row = rowBase + wave * 16 + g * 4 + r;
      out[row * 128 + col] = (acc[cb][r] - mu[r]) * inv[r] * gv + bv_;
    }
  }
}

// ---------------------------------------------------------------------------
extern "C" void kernel_launch(void* const* d_in, const int* in_sizes, int n_in,
                              void* d_out, int out_size, void* d_ws, size_t ws_size,
                              hipStream_t stream) {
  const float* x   = (const float*)d_in[0];
  const int*   ei  = (const int*)d_in[1];
  const float* ea  = (const float*)d_in[2];
  const float* Wq  = (const float*)d_in[3];
  const float* bq  = (const float*)d_in[4];
  const float* Wk  = (const float*)d_in[5];
  const float* bk  = (const float*)d_in[6];
  const float* Wv  = (const float*)d_in[7];
  const float* bv  = (const float*)d_in[8];
  const float* Wf  = (const float*)d_in[9];
  const float* bf  = (const float*)d_in[10];
  const float* Wo  = (const float*)d_in[11];
  const float* bo  = (const float*)d_in[12];
  const float* lng = (const float*)d_in[13];
  const float* lnb = (const float*)d_in[14];
  float* out = (float*)d_out;

  const size_t NQ = (size_t)B_ * N_ * HID_;  // 5,120,000

  char* base = (char*)d_ws;
  size_t off = 0;
  float* Q    = (float*)(base + off); off += NQ * 4;                 // 20.48MB
  float* agg  = (float*)(base + off); off += NQ * 4;                 // 20.48MB
  float* eas  = (float*)(base + off); off += (size_t)E_ * 16 * 4;    // 10.24MB
  unsigned char* kv8 = (unsigned char*)(base + off);
  off += (size_t)B_ * N_ * 256;                                      // 10.24MB
  short* wt   = (short*)(base + off); off += 4 * 16384 * 2;          // 128KB
  int*  cnt    = (int*)(base + off); off += N_ * 4;
  int*  rowptr = (int*)(base + off); off += (N_ + 1) * 4;
  int*  fill   = (int*)(base + off); off += N_ * 4;
  int*  esrc   = (int*)(base + off); off += E_ * 4;

  hipMemsetAsync(cnt, 0, N_ * sizeof(int), stream);

  wt_prep<<<256, 256, 0, stream>>>(Wq, Wk, Wv, Wo, wt);
  qkv_mfma<<<(B_ * N_) / 64, 256, 0, stream>>>(x, wt, bq, bk, bv, Q, kv8);
  csr_hist<<<(E_ + 255) / 256, 256, 0, stream>>>(ei, cnt);
  csr_scan<<<1, 1024, 0, stream>>>(cnt, rowptr, fill);
  csr_scatter<<<(E_ + 255) / 256, 256, 0, stream>>>(ei, ea, fill, esrc, eas);
  fused_attn<<<N_, 256, 0, stream>>>(rowptr, esrc, eas, Wf, bf, Q, kv8, agg);
  out_ln_mfma<<<(B_ * N_) / 64, 256, 0, stream>>>(agg, wt + 3 * 16384, bo, x, lng, lnb, out);
}

// Round 13
// 211.803 us; speedup vs baseline: 1.1187x; 1.1187x over previous
//
#include <hip/hip_runtime.h>
#include <hip/hip_bf16.h>

#define B_ 4
#define N_ 10000
#define E_ 160000
#define D_ 128
#define H_ 4
#define HID_ 128
#define DK_ 32
#define DE_ 16

typedef __attribute__((ext_vector_type(8))) short short8v;
typedef __attribute__((ext_vector_type(4))) short short4v;
typedef __attribute__((ext_vector_type(4))) float f32x4;
typedef __attribute__((ext_vector_type(2))) float f32x2;

// fp32 -> bf16 bits, round-to-nearest-even
__device__ __forceinline__ short bfb(float f) {
  union { float f; unsigned u; } c; c.f = f;
  unsigned u = c.u + 0x7FFFu + ((c.u >> 16) & 1u);
  return (short)(u >> 16);
}

// fp32 -> fp8 e4m3 (OCP on gfx950)
__device__ __forceinline__ unsigned char f2fp8(float f) {
  int r = __builtin_amdgcn_cvt_pk_fp8_f32(f, f, 0, false);
  return (unsigned char)(r & 0xff);
}
// 2 packed fp8 -> 2 fp32
__device__ __forceinline__ f32x2 fp8x2f(unsigned short u) {
  return __builtin_amdgcn_cvt_pk_f32_fp8((int)u, false);
}

// ---------------------------------------------------------------------------
// P0: W^T bf16 prep. wt[m][n][k] = bf16(W_m[k*128+n]),  m: 0=q 1=k 2=v 3=o
// ---------------------------------------------------------------------------
__global__ __launch_bounds__(256) void wt_prep(
    const float* __restrict__ Wq, const float* __restrict__ Wk,
    const float* __restrict__ Wv, const float* __restrict__ Wo,
    short* __restrict__ wt) {
  const float* Ws[4] = {Wq, Wk, Wv, Wo};
  const int i = blockIdx.x * 256 + threadIdx.x;   // 0..65535
  const int m = i >> 14;
  const int k = (i >> 7) & 127;
  const int n = i & 127;
  wt[(size_t)m * 16384 + n * 128 + k] = bfb(Ws[m][k * 128 + n]);
}

// ---------------------------------------------------------------------------
// K1: QKV projection via MFMA. block = 256 (4 waves), 64 rows/block.
// Q -> fp32 [b][n][128]; K,V -> fp8 e4m3 kv8[n][b][0:128 = K | 128:256 = V]
// ---------------------------------------------------------------------------
__global__ __launch_bounds__(256) void qkv_mfma(
    const float* __restrict__ x, const short* __restrict__ wt,
    const float* __restrict__ bq, const float* __restrict__ bk,
    const float* __restrict__ bv,
    float* __restrict__ Q, unsigned char* __restrict__ kv8) {
  __shared__ short xs[64][136];
  const int tid  = threadIdx.x;
  const int lane = tid & 63;
  const int wave = tid >> 6;
  const int ln15 = lane & 15;
  const int g    = lane >> 4;
  const long rowBase = (long)blockIdx.x * 64;

  for (int i = tid; i < 64 * 32; i += 256) {
    const int r  = i >> 5;
    const int c4 = (i & 31) * 4;
    const float4 v = *(const float4*)(x + (rowBase + r) * 128 + c4);
    short4v sv; sv.x = bfb(v.x); sv.y = bfb(v.y); sv.z = bfb(v.z); sv.w = bfb(v.w);
    *(short4v*)&xs[r][c4] = sv;
  }
  __syncthreads();

  short8v af[4];
#pragma unroll
  for (int kk = 0; kk < 4; ++kk)
    af[kk] = *(const short8v*)&xs[wave * 16 + ln15][kk * 32 + g * 8];

  const float* bs[3] = {bq, bk, bv};

  int bbv[4], nnv[4];
#pragma unroll
  for (int r = 0; r < 4; ++r) {
    const long row = rowBase + wave * 16 + g * 4 + r;
    bbv[r] = (int)(row / N_);
    nnv[r] = (int)(row - (long)bbv[r] * N_);
  }

#pragma unroll
  for (int m = 0; m < 3; ++m) {
    const short* Wt = wt + (size_t)m * 16384;
    f32x4 acc[8];
#pragma unroll
    for (int cb = 0; cb < 8; ++cb) acc[cb] = (f32x4){0.f, 0.f, 0.f, 0.f};

#pragma unroll
    for (int kk = 0; kk < 4; ++kk) {
#pragma unroll
      for (int cb = 0; cb < 8; ++cb) {
        const short8v bfr =
            *(const short8v*)(Wt + (cb * 16 + ln15) * 128 + kk * 32 + g * 8);
        acc[cb] = __builtin_amdgcn_mfma_f32_16x16x32_bf16(af[kk], bfr, acc[cb], 0, 0, 0);
      }
    }

    const float* bias = bs[m];
#pragma unroll
    for (int cb = 0; cb < 8; ++cb) {
      const int col = cb * 16 + ln15;
      const float bv_ = bias[col];
#pragma unroll
      for (int r = 0; r < 4; ++r) {
        const float val = acc[cb][r] + bv_;
        if (m == 0) {
          const long row = rowBase + wave * 16 + g * 4 + r;
          Q[row * 128 + col] = val;
        } else {
          kv8[(((size_t)nnv[r] * 4 + bbv[r]) << 8) + (m - 1) * 128 + col] = f2fp8(val);
        }
      }
    }
  }
}

// ---------------------------------------------------------------------------
// CSR build
// ---------------------------------------------------------------------------
__global__ __launch_bounds__(256) void csr_hist(const int* __restrict__ ei,
                                                int* __restrict__ cnt) {
  const int e = blockIdx.x * 256 + threadIdx.x;
  if (e < E_) atomicAdd(&cnt[ei[E_ + e]], 1);
}

__global__ __launch_bounds__(1024) void csr_scan(const int* __restrict__ cnt,
                                                 int* __restrict__ rowptr,
                                                 int* __restrict__ fill) {
  __shared__ int part[1024];
  const int t = threadIdx.x;
  int local[10];
  int sum = 0;
#pragma unroll
  for (int i = 0; i < 10; ++i) {
    const int idx = t * 10 + i;
    local[i] = sum;
    sum += (idx < N_) ? cnt[idx] : 0;
  }
  part[t] = sum;
  __syncthreads();
  for (int off = 1; off < 1024; off <<= 1) {
    const int v = (t >= off) ? part[t - off] : 0;
    __syncthreads();
    part[t] += v;
    __syncthreads();
  }
  const int excl = (t == 0) ? 0 : part[t - 1];
#pragma unroll
  for (int i = 0; i < 10; ++i) {
    const int idx = t * 10 + i;
    if (idx <= N_) {
      const int o = excl + local[i];
      rowptr[idx] = o;
      if (idx < N_) fill[idx] = o;
    }
  }
}

// scatter: CSR-ordered src + CSR-ordered copy of edge_attr
__global__ __launch_bounds__(256) void csr_scatter(
    const int* __restrict__ ei, const float* __restrict__ ea,
    int* __restrict__ fill, int* __restrict__ esrc, float* __restrict__ eas) {
  const int e = blockIdx.x * 256 + threadIdx.x;
  if (e < E_) {
    const int dst = ei[E_ + e];
    const int pos = atomicAdd(&fill[dst], 1);
    esrc[pos] = ei[e];
    const float4* s4 = (const float4*)(ea + (size_t)e * 16);
    float4* d4 = (float4*)(eas + (size_t)pos * 16);
    d4[0] = s4[0]; d4[1] = s4[1]; d4[2] = s4[2]; d4[3] = s4[3];
  }
}

// ---------------------------------------------------------------------------
// K2: fused FiLM + logits + softmax + aggregation.  (R9 inner loop, finer
// launch geometry: block = 128 = 2 waves -> (node, head-pair); wave = head.)
// lane = 4*p + b  (p = dim-pair 0..15, b = batch).
// K,V gathered as fp8 (ushort = 2 cols), decoded via v_cvt_pk_f32_fp8.
// FiLM once per edge (j-partials across b-lanes, shfl_xor 1,2);
// logit reduce over p-lanes (shfl_xor 4,8,16,32). No LDS, no barriers.
// Single-pass softmax (no max): acc=sum(ex*V), se=sum(ex); agg=acc/se.
// Edge loop unrolled x4 with batched load issue + serial remainder.
// ---------------------------------------------------------------------------
__device__ __forceinline__ void edge_step(
    const float4 ev, const unsigned short ku, const unsigned short vu,
    const float2 q2, const float2* wg, const float2* wb,
    const float bg0, const float bg1, const float bb0, const float bb1,
    float& acc0, float& acc1, float& se) {
  float g0 = ev.x * wg[0].x, g1 = ev.x * wg[0].y;
  float t0 = ev.x * wb[0].x, t1 = ev.x * wb[0].y;
  g0 = fmaf(ev.y, wg[1].x, g0); g1 = fmaf(ev.y, wg[1].y, g1);
  t0 = fmaf(ev.y, wb[1].x, t0); t1 = fmaf(ev.y, wb[1].y, t1);
  g0 = fmaf(ev.z, wg[2].x, g0); g1 = fmaf(ev.z, wg[2].y, g1);
  t0 = fmaf(ev.z, wb[2].x, t0); t1 = fmaf(ev.z, wb[2].y, t1);
  g0 = fmaf(ev.w, wg[3].x, g0); g1 = fmaf(ev.w, wg[3].y, g1);
  t0 = fmaf(ev.w, wb[3].x, t0); t1 = fmaf(ev.w, wb[3].y, t1);
  g0 += __shfl_xor(g0, 1); g1 += __shfl_xor(g1, 1);
  t0 += __shfl_xor(t0, 1); t1 += __shfl_xor(t1, 1);
  g0 += __shfl_xor(g0, 2); g1 += __shfl_xor(g1, 2);
  t0 += __shfl_xor(t0, 2); t1 += __shfl_xor(t1, 2);
  g0 += bg0; g1 += bg1;
  t0 += bb0; t1 += bb1;
  const f32x2 kk = fp8x2f(ku);
  const f32x2 vv = fp8x2f(vu);
  float pl = fmaf(q2.x, fmaf(kk.x, g0, t0), q2.y * fmaf(kk.y, g1, t1));
  pl += __shfl_xor(pl, 4);
  pl += __shfl_xor(pl, 8);
  pl += __shfl_xor(pl, 16);
  pl += __shfl_xor(pl, 32);
  const float ex = __expf(pl * 0.17677669529663687f);  // 1/sqrt(32)
  se += ex;
  acc0 = fmaf(ex, vv.x, acc0);
  acc1 = fmaf(ex, vv.y, acc1);
}

__global__ __launch_bounds__(128) void fused_attn(
    const int* __restrict__ rowptr, const int* __restrict__ esrc,
    const float* __restrict__ eas, const float* __restrict__ Wf,
    const float* __restrict__ bf, const float* __restrict__ Q,
    const unsigned char* __restrict__ kv8, float* __restrict__ agg) {
  const int node = blockIdx.x >> 1;
  const int h    = ((blockIdx.x & 1) << 1) + (threadIdx.x >> 6);  // head
  const int lane = threadIdx.x & 63;
  const int b    = lane & 3;           // batch
  const int p    = lane >> 2;          // dim-pair within head
  const int col0 = h * 32 + 2 * p;

  // Wf slice: rows j in [4b, 4b+4), gamma cols {col0,col0+1}, beta cols {128+col0,...}
  float2 wg[4], wb[4];
#pragma unroll
  for (int jj = 0; jj < 4; ++jj) {
    wg[jj] = *(const float2*)(Wf + (4 * b + jj) * 256 + col0);
    wb[jj] = *(const float2*)(Wf + (4 * b + jj) * 256 + 128 + col0);
  }
  const float bg0 = 1.f + bf[col0], bg1 = 1.f + bf[col0 + 1];
  const float bb0 = bf[128 + col0], bb1 = bf[129 + col0];

  const float2 q2 = *(const float2*)(Q + ((size_t)b * N_ + node) * 128 + col0);

  const int beg = rowptr[node], end = rowptr[node + 1];
  float acc0 = 0.f, acc1 = 0.f, se = 0.f;

  int i = beg;
  for (; i + 4 <= end; i += 4) {
    const int s0 = esrc[i + 0];
    const int s1 = esrc[i + 1];
    const int s2 = esrc[i + 2];
    const int s3 = esrc[i + 3];
    const float4 e0 = *(const float4*)(eas + (size_t)(i + 0) * 16 + 4 * b);
    const float4 e1 = *(const float4*)(eas + (size_t)(i + 1) * 16 + 4 * b);
    const float4 e2 = *(const float4*)(eas + (size_t)(i + 2) * 16 + 4 * b);
    const float4 e3 = *(const float4*)(eas + (size_t)(i + 3) * 16 + 4 * b);
    const unsigned char* kp0 = kv8 + ((((size_t)s0 << 2) + b) << 8) + col0;
    const unsigned char* kp1 = kv8 + ((((size_t)s1 << 2) + b) << 8) + col0;
    const unsigned char* kp2 = kv8 + ((((size_t)s2 << 2) + b) << 8) + col0;
    const unsigned char* kp3 = kv8 + ((((size_t)s3 << 2) + b) << 8) + col0;
    const unsigned short kk0 = *(const unsigned short*)kp0;
    const unsigned short vv0 = *(const unsigned short*)(kp0 + 128);
    const unsigned short kk1 = *(const unsigned short*)kp1;
    const unsigned short vv1 = *(const unsigned short*)(kp1 + 128);
    const unsigned short kk2 = *(const unsigned short*)kp2;
    const unsigned short vv2 = *(const unsigned short*)(kp2 + 128);
    const unsigned short kk3 = *(const unsigned short*)kp3;
    const unsigned short vv3 = *(const unsigned short*)(kp3 + 128);

    edge_step(e0, kk0, vv0, q2, wg, wb, bg0, bg1, bb0, bb1, acc0, acc1, se);
    edge_step(e1, kk1, vv1, q2, wg, wb, bg0, bg1, bb0, bb1, acc0, acc1, se);
    edge_step(e2, kk2, vv2, q2, wg, wb, bg0, bg1, bb0, bb1, acc0, acc1, se);
    edge_step(e3, kk3, vv3, q2, wg, wb, bg0, bg1, bb0, bb1, acc0, acc1, se);
  }
  for (; i < end; ++i) {
    const int s0 = esrc[i];
    const float4 e0 = *(const float4*)(eas + (size_t)i * 16 + 4 * b);
    const unsigned char* kp0 = kv8 + ((((size_t)s0 << 2) + b) << 8) + col0;
    const unsigned short kk0 = *(const unsigned short*)kp0;
    const unsigned short vv0 = *(const unsigned short*)(kp0 + 128);
    edge_step(e0, kk0, vv0, q2, wg, wb, bg0, bg1, bb0, bb1, acc0, acc1, se);
  }

  const float inv = (end > beg) ? 1.f / se : 0.f;
  float2 o; o.x = acc0 * inv; o.y = acc1 * inv;
  *(float2*)(agg + ((size_t)b * N_ + node) * 128 + col0) = o;
}

// ---------------------------------------------------------------------------
// K4: y = agg @ Wo + bo (MFMA); h = x + y; LayerNorm(h) -> out
// ---------------------------------------------------------------------------
__global__ __launch_bounds__(256) void out_ln_mfma(
    const float* __restrict__ agg, const short* __restrict__ wto,
    const float* __restrict__ bo, const float* __restrict__ x,
    const float* __restrict__ lng, const float* __restrict__ lnb,
    float* __restrict__ out) {
  __shared__ short as_[64][136];
  const int tid  = threadIdx.x;
  const int lane = tid & 63;
  const int wave = tid >> 6;
  const int ln15 = lane & 15;
  const int g    = lane >> 4;
  const long rowBase = (long)blockIdx.x * 64;

  for (int i = tid; i < 64 * 32; i += 256) {
    const int r  = i >> 5;
    const int c4 = (i & 31) * 4;
    const float4 v = *(const float4*)(agg + (rowBase + r) * 128 + c4);
    short4v sv; sv.x = bfb(v.x); sv.y = bfb(v.y); sv.z = bfb(v.z); sv.w = bfb(v.w);
    *(short4v*)&as_[r][c4] = sv;
  }
  __syncthreads();

  short8v af[4];
#pragma unroll
  for (int kk = 0; kk < 4; ++kk)
    af[kk] = *(const short8v*)&as_[wave * 16 + ln15][kk * 32 + g * 8];

  f32x4 acc[8];
#pragma unroll
  for (int cb = 0; cb < 8; ++cb) acc[cb] = (f32x4){0.f, 0.f, 0.f, 0.f};

#pragma unroll
  for (int kk = 0; kk < 4; ++kk) {
#pragma unroll
    for (int cb = 0; cb < 8; ++cb) {
      const short8v bfr =
          *(const short8v*)(wto + (cb * 16 + ln15) * 128 + kk * 32 + g * 8);
      acc[cb] = __builtin_amdgcn_mfma_f32_16x16x32_bf16(af[kk], bfr, acc[cb], 0, 0, 0);
    }
  }

#pragma unroll
  for (int cb = 0; cb < 8; ++cb) {
    const int col = cb * 16 + ln15;
    const float bov = bo[col];
#pragma unroll
    for (int r = 0; r < 4; ++r) {
      const long row = rowBase + wave * 16 + g * 4 + r;
      acc[cb][r] += bov + x[row * 128 + col];
    }
  }

  float s1[4], s2[4];
#pragma unroll
  for (int r = 0; r < 4; ++r) {
    s1[r] = 0.f; s2[r] = 0.f;
#pragma unroll
    for (int cb = 0; cb < 8; ++cb) {
      s1[r] += acc[cb][r];
      s2[r] = fmaf(acc[cb][r], acc[cb][r], s2[r]);
    }
  }
#pragma unroll
  for (int m = 1; m < 16; m <<= 1) {
#pragma unroll
    for (int r = 0; r < 4; ++r) {
      s1[r] += __shfl_xor(s1[r], m);
      s2[r] += __shfl_xor(s2[r], m);
    }
  }
  float mu[4], inv[4];
#pragma unroll
  for (int r = 0; r < 4; ++r) {
    mu[r] = s1[r] * (1.f / 128.f);
    const float var = s2[r] * (1.f / 128.f) - mu[r] * mu[r];
    inv[r] = rsqrtf(var + 1e-5f);
  }

#pragma unroll
  for (int cb = 0; cb < 8; ++cb) {
    const int col = cb * 16 + ln15;
    const float gv = lng[col], bv_ = lnb[col];
#pragma unroll
    for (int r = 0; r < 4; ++r) {
      const long row = rowBase + wave * 16 + g * 4 + r;
      out[row * 128 + col] = (acc[cb][r] - mu[r]) * inv[r] * gv + bv_;
    }
  }
}

// ---------------------------------------------------------------------------
extern "C" void kernel_launch(void* const* d_in, const int* in_sizes, int n_in,
                              void* d_out, int out_size, void* d_ws, size_t ws_size,
                              hipStream_t stream) {
  const float* x   = (const float*)d_in[0];
  const int*   ei  = (const int*)d_in[1];
  const float* ea  = (const float*)d_in[2];
  const float* Wq  = (const float*)d_in[3];
  const float* bq  = (const float*)d_in[4];
  const float* Wk  = (const float*)d_in[5];
  const float* bk  = (const float*)d_in[6];
  const float* Wv  = (const float*)d_in[7];
  const float* bv  = (const float*)d_in[8];
  const float* Wf  = (const float*)d_in[9];
  const float* bf  = (const float*)d_in[10];
  const float* Wo  = (const float*)d_in[11];
  const float* bo  = (const float*)d_in[12];
  const float* lng = (const float*)d_in[13];
  const float* lnb = (const float*)d_in[14];
  float* out = (float*)d_out;

  const size_t NQ = (size_t)B_ * N_ * HID_;  // 5,120,000

  char* base = (char*)d_ws;
  size_t off = 0;
  float* Q    = (float*)(base + off); off += NQ * 4;                 // 20.48MB
  float* agg  = (float*)(base + off); off += NQ * 4;                 // 20.48MB
  float* eas  = (float*)(base + off); off += (size_t)E_ * 16 * 4;    // 10.24MB
  unsigned char* kv8 = (unsigned char*)(base + off);
  off += (size_t)B_ * N_ * 256;                                      // 10.24MB
  short* wt   = (short*)(base + off); off += 4 * 16384 * 2;          // 128KB
  int*  cnt    = (int*)(base + off); off += N_ * 4;
  int*  rowptr = (int*)(base + off); off += (N_ + 1) * 4;
  int*  fill   = (int*)(base + off); off += N_ * 4;
  int*  esrc   = (int*)(base + off); off += E_ * 4;

  hipMemsetAsync(cnt, 0, N_ * sizeof(int), stream);

  wt_prep<<<256, 256, 0, stream>>>(Wq, Wk, Wv, Wo, wt);
  qkv_mfma<<<(B_ * N_) / 64, 256, 0, stream>>>(x, wt, bq, bk, bv, Q, kv8);
  csr_hist<<<(E_ + 255) / 256, 256, 0, stream>>>(ei, cnt);
  csr_scan<<<1, 1024, 0, stream>>>(cnt, rowptr, fill);
  csr_scatter<<<(E_ + 255) / 256, 256, 0, stream>>>(ei, ea, fill, esrc, eas);
  fused_attn<<<N_ * 2, 128, 0, stream>>>(rowptr, esrc, eas, Wf, bf, Q, kv8, agg);
  out_ln_mfma<<<(B_ * N_) / 64, 256, 0, stream>>>(agg, wt + 3 * 16384, bo, x, lng, lnb, out);
}

// Round 14
// 209.392 us; speedup vs baseline: 1.1316x; 1.0115x over previous
//
#include <hip/hip_runtime.h>
#include <hip/hip_bf16.h>

#define B_ 4
#define N_ 10000
#define E_ 160000
#define D_ 128
#define H_ 4
#define HID_ 128
#define DK_ 32
#define DE_ 16
#define PGRID 2048   // persistent grid for fused_attn

typedef __attribute__((ext_vector_type(8))) short short8v;
typedef __attribute__((ext_vector_type(4))) short short4v;
typedef __attribute__((ext_vector_type(4))) float f32x4;
typedef __attribute__((ext_vector_type(2))) float f32x2;

// fp32 -> bf16 bits, round-to-nearest-even
__device__ __forceinline__ short bfb(float f) {
  union { float f; unsigned u; } c; c.f = f;
  unsigned u = c.u + 0x7FFFu + ((c.u >> 16) & 1u);
  return (short)(u >> 16);
}

// fp32 -> fp8 e4m3 (OCP on gfx950)
__device__ __forceinline__ unsigned char f2fp8(float f) {
  int r = __builtin_amdgcn_cvt_pk_fp8_f32(f, f, 0, false);
  return (unsigned char)(r & 0xff);
}
// 2 packed fp8 -> 2 fp32
__device__ __forceinline__ f32x2 fp8x2f(unsigned short u) {
  return __builtin_amdgcn_cvt_pk_f32_fp8((int)u, false);
}

// ---------------------------------------------------------------------------
// P0: W^T bf16 prep. wt[m][n][k] = bf16(W_m[k*128+n]),  m: 0=q 1=k 2=v 3=o
// ---------------------------------------------------------------------------
__global__ __launch_bounds__(256) void wt_prep(
    const float* __restrict__ Wq, const float* __restrict__ Wk,
    const float* __restrict__ Wv, const float* __restrict__ Wo,
    short* __restrict__ wt) {
  const float* Ws[4] = {Wq, Wk, Wv, Wo};
  const int i = blockIdx.x * 256 + threadIdx.x;   // 0..65535
  const int m = i >> 14;
  const int k = (i >> 7) & 127;
  const int n = i & 127;
  wt[(size_t)m * 16384 + n * 128 + k] = bfb(Ws[m][k * 128 + n]);
}

// ---------------------------------------------------------------------------
// K1: QKV projection via MFMA. block = 256 (4 waves), 64 rows/block.
// Q -> fp32 [b][n][128]; K,V -> fp8 e4m3 kv8[n][b][0:128 = K | 128:256 = V]
// ---------------------------------------------------------------------------
__global__ __launch_bounds__(256) void qkv_mfma(
    const float* __restrict__ x, const short* __restrict__ wt,
    const float* __restrict__ bq, const float* __restrict__ bk,
    const float* __restrict__ bv,
    float* __restrict__ Q, unsigned char* __restrict__ kv8) {
  __shared__ short xs[64][136];
  const int tid  = threadIdx.x;
  const int lane = tid & 63;
  const int wave = tid >> 6;
  const int ln15 = lane & 15;
  const int g    = lane >> 4;
  const long rowBase = (long)blockIdx.x * 64;

  for (int i = tid; i < 64 * 32; i += 256) {
    const int r  = i >> 5;
    const int c4 = (i & 31) * 4;
    const float4 v = *(const float4*)(x + (rowBase + r) * 128 + c4);
    short4v sv; sv.x = bfb(v.x); sv.y = bfb(v.y); sv.z = bfb(v.z); sv.w = bfb(v.w);
    *(short4v*)&xs[r][c4] = sv;
  }
  __syncthreads();

  short8v af[4];
#pragma unroll
  for (int kk = 0; kk < 4; ++kk)
    af[kk] = *(const short8v*)&xs[wave * 16 + ln15][kk * 32 + g * 8];

  const float* bs[3] = {bq, bk, bv};

  int bbv[4], nnv[4];
#pragma unroll
  for (int r = 0; r < 4; ++r) {
    const long row = rowBase + wave * 16 + g * 4 + r;
    bbv[r] = (int)(row / N_);
    nnv[r] = (int)(row - (long)bbv[r] * N_);
  }

#pragma unroll
  for (int m = 0; m < 3; ++m) {
    const short* Wt = wt + (size_t)m * 16384;
    f32x4 acc[8];
#pragma unroll
    for (int cb = 0; cb < 8; ++cb) acc[cb] = (f32x4){0.f, 0.f, 0.f, 0.f};

#pragma unroll
    for (int kk = 0; kk < 4; ++kk) {
#pragma unroll
      for (int cb = 0; cb < 8; ++cb) {
        const short8v bfr =
            *(const short8v*)(Wt + (cb * 16 + ln15) * 128 + kk * 32 + g * 8);
        acc[cb] = __builtin_amdgcn_mfma_f32_16x16x32_bf16(af[kk], bfr, acc[cb], 0, 0, 0);
      }
    }

    const float* bias = bs[m];
#pragma unroll
    for (int cb = 0; cb < 8; ++cb) {
      const int col = cb * 16 + ln15;
      const float bv_ = bias[col];
#pragma unroll
      for (int r = 0; r < 4; ++r) {
        const float val = acc[cb][r] + bv_;
        if (m == 0) {
          const long row = rowBase + wave * 16 + g * 4 + r;
          Q[row * 128 + col] = val;
        } else {
          kv8[(((size_t)nnv[r] * 4 + bbv[r]) << 8) + (m - 1) * 128 + col] = f2fp8(val);
        }
      }
    }
  }
}

// ---------------------------------------------------------------------------
// CSR build
// ---------------------------------------------------------------------------
__global__ __launch_bounds__(256) void csr_hist(const int* __restrict__ ei,
                                                int* __restrict__ cnt) {
  const int e = blockIdx.x * 256 + threadIdx.x;
  if (e < E_) atomicAdd(&cnt[ei[E_ + e]], 1);
}

__global__ __launch_bounds__(1024) void csr_scan(const int* __restrict__ cnt,
                                                 int* __restrict__ rowptr,
                                                 int* __restrict__ fill) {
  __shared__ int part[1024];
  const int t = threadIdx.x;
  int local[10];
  int sum = 0;
#pragma unroll
  for (int i = 0; i < 10; ++i) {
    const int idx = t * 10 + i;
    local[i] = sum;
    sum += (idx < N_) ? cnt[idx] : 0;
  }
  part[t] = sum;
  __syncthreads();
  for (int off = 1; off < 1024; off <<= 1) {
    const int v = (t >= off) ? part[t - off] : 0;
    __syncthreads();
    part[t] += v;
    __syncthreads();
  }
  const int excl = (t == 0) ? 0 : part[t - 1];
#pragma unroll
  for (int i = 0; i < 10; ++i) {
    const int idx = t * 10 + i;
    if (idx <= N_) {
      const int o = excl + local[i];
      rowptr[idx] = o;
      if (idx < N_) fill[idx] = o;
    }
  }
}

// scatter: CSR-ordered src + CSR-ordered copy of edge_attr
__global__ __launch_bounds__(256) void csr_scatter(
    const int* __restrict__ ei, const float* __restrict__ ea,
    int* __restrict__ fill, int* __restrict__ esrc, float* __restrict__ eas) {
  const int e = blockIdx.x * 256 + threadIdx.x;
  if (e < E_) {
    const int dst = ei[E_ + e];
    const int pos = atomicAdd(&fill[dst], 1);
    esrc[pos] = ei[e];
    const float4* s4 = (const float4*)(ea + (size_t)e * 16);
    float4* d4 = (float4*)(eas + (size_t)pos * 16);
    d4[0] = s4[0]; d4[1] = s4[1]; d4[2] = s4[2]; d4[3] = s4[3];
  }
}

// ---------------------------------------------------------------------------
// K2: fused FiLM + logits + softmax + aggregation.  (R9 inner loop,
// PERSISTENT blocks: grid = 2048, block = 256 = 4 waves (wave = head);
// block grid-strides over nodes -> zero block churn, full wave residency.)
// lane = 4*p + b  (p = dim-pair 0..15, b = batch).
// K,V gathered as fp8 (ushort = 2 cols), decoded via v_cvt_pk_f32_fp8.
// FiLM once per edge (j-partials across b-lanes, shfl_xor 1,2);
// logit reduce over p-lanes (shfl_xor 4,8,16,32). No LDS, no barriers.
// Single-pass softmax (no max): acc=sum(ex*V), se=sum(ex); agg=acc/se.
// Edge loop unrolled x4 with batched load issue + serial remainder.
// ---------------------------------------------------------------------------
__device__ __forceinline__ void edge_step(
    const float4 ev, const unsigned short ku, const unsigned short vu,
    const float2 q2, const float2* wg, const float2* wb,
    const float bg0, const float bg1, const float bb0, const float bb1,
    float& acc0, float& acc1, float& se) {
  float g0 = ev.x * wg[0].x, g1 = ev.x * wg[0].y;
  float t0 = ev.x * wb[0].x, t1 = ev.x * wb[0].y;
  g0 = fmaf(ev.y, wg[1].x, g0); g1 = fmaf(ev.y, wg[1].y, g1);
  t0 = fmaf(ev.y, wb[1].x, t0); t1 = fmaf(ev.y, wb[1].y, t1);
  g0 = fmaf(ev.z, wg[2].x, g0); g1 = fmaf(ev.z, wg[2].y, g1);
  t0 = fmaf(ev.z, wb[2].x, t0); t1 = fmaf(ev.z, wb[2].y, t1);
  g0 = fmaf(ev.w, wg[3].x, g0); g1 = fmaf(ev.w, wg[3].y, g1);
  t0 = fmaf(ev.w, wb[3].x, t0); t1 = fmaf(ev.w, wb[3].y, t1);
  g0 += __shfl_xor(g0, 1); g1 += __shfl_xor(g1, 1);
  t0 += __shfl_xor(t0, 1); t1 += __shfl_xor(t1, 1);
  g0 += __shfl_xor(g0, 2); g1 += __shfl_xor(g1, 2);
  t0 += __shfl_xor(t0, 2); t1 += __shfl_xor(t1, 2);
  g0 += bg0; g1 += bg1;
  t0 += bb0; t1 += bb1;
  const f32x2 kk = fp8x2f(ku);
  const f32x2 vv = fp8x2f(vu);
  float pl = fmaf(q2.x, fmaf(kk.x, g0, t0), q2.y * fmaf(kk.y, g1, t1));
  pl += __shfl_xor(pl, 4);
  pl += __shfl_xor(pl, 8);
  pl += __shfl_xor(pl, 16);
  pl += __shfl_xor(pl, 32);
  const float ex = __expf(pl * 0.17677669529663687f);  // 1/sqrt(32)
  se += ex;
  acc0 = fmaf(ex, vv.x, acc0);
  acc1 = fmaf(ex, vv.y, acc1);
}

__global__ __launch_bounds__(256) void fused_attn(
    const int* __restrict__ rowptr, const int* __restrict__ esrc,
    const float* __restrict__ eas, const float* __restrict__ Wf,
    const float* __restrict__ bf, const float* __restrict__ Q,
    const unsigned char* __restrict__ kv8, float* __restrict__ agg) {
  const int h    = threadIdx.x >> 6;   // wave = head
  const int lane = threadIdx.x & 63;
  const int b    = lane & 3;           // batch
  const int p    = lane >> 2;          // dim-pair within head
  const int col0 = h * 32 + 2 * p;

  // Wf slice: rows j in [4b, 4b+4), gamma cols {col0,col0+1}, beta cols {128+col0,...}
  float2 wg[4], wb[4];
#pragma unroll
  for (int jj = 0; jj < 4; ++jj) {
    wg[jj] = *(const float2*)(Wf + (4 * b + jj) * 256 + col0);
    wb[jj] = *(const float2*)(Wf + (4 * b + jj) * 256 + 128 + col0);
  }
  const float bg0 = 1.f + bf[col0], bg1 = 1.f + bf[col0 + 1];
  const float bb0 = bf[128 + col0], bb1 = bf[129 + col0];

  for (int node = blockIdx.x; node < N_; node += PGRID) {
    const float2 q2 = *(const float2*)(Q + ((size_t)b * N_ + node) * 128 + col0);
    const int beg = rowptr[node], end = rowptr[node + 1];
    float acc0 = 0.f, acc1 = 0.f, se = 0.f;

    int i = beg;
    for (; i + 4 <= end; i += 4) {
      const int s0 = esrc[i + 0];
      const int s1 = esrc[i + 1];
      const int s2 = esrc[i + 2];
      const int s3 = esrc[i + 3];
      const float4 e0 = *(const float4*)(eas + (size_t)(i + 0) * 16 + 4 * b);
      const float4 e1 = *(const float4*)(eas + (size_t)(i + 1) * 16 + 4 * b);
      const float4 e2 = *(const float4*)(eas + (size_t)(i + 2) * 16 + 4 * b);
      const float4 e3 = *(const float4*)(eas + (size_t)(i + 3) * 16 + 4 * b);
      const unsigned char* kp0 = kv8 + ((((size_t)s0 << 2) + b) << 8) + col0;
      const unsigned char* kp1 = kv8 + ((((size_t)s1 << 2) + b) << 8) + col0;
      const unsigned char* kp2 = kv8 + ((((size_t)s2 << 2) + b) << 8) + col0;
      const unsigned char* kp3 = kv8 + ((((size_t)s3 << 2) + b) << 8) + col0;
      const unsigned short kk0 = *(const unsigned short*)kp0;
      const unsigned short vv0 = *(const unsigned short*)(kp0 + 128);
      const unsigned short kk1 = *(const unsigned short*)kp1;
      const unsigned short vv1 = *(const unsigned short*)(kp1 + 128);
      const unsigned short kk2 = *(const unsigned short*)kp2;
      const unsigned short vv2 = *(const unsigned short*)(kp2 + 128);
      const unsigned short kk3 = *(const unsigned short*)kp3;
      const unsigned short vv3 = *(const unsigned short*)(kp3 + 128);

      edge_step(e0, kk0, vv0, q2, wg, wb, bg0, bg1, bb0, bb1, acc0, acc1, se);
      edge_step(e1, kk1, vv1, q2, wg, wb, bg0, bg1, bb0, bb1, acc0, acc1, se);
      edge_step(e2, kk2, vv2, q2, wg, wb, bg0, bg1, bb0, bb1, acc0, acc1, se);
      edge_step(e3, kk3, vv3, q2, wg, wb, bg0, bg1, bb0, bb1, acc0, acc1, se);
    }
    for (; i < end; ++i) {
      const int s0 = esrc[i];
      const float4 e0 = *(const float4*)(eas + (size_t)i * 16 + 4 * b);
      const unsigned char* kp0 = kv8 + ((((size_t)s0 << 2) + b) << 8) + col0;
      const unsigned short kk0 = *(const unsigned short*)kp0;
      const unsigned short vv0 = *(const unsigned short*)(kp0 + 128);
      edge_step(e0, kk0, vv0, q2, wg, wb, bg0, bg1, bb0, bb1, acc0, acc1, se);
    }

    const float inv = (end > beg) ? 1.f / se : 0.f;
    float2 o; o.x = acc0 * inv; o.y = acc1 * inv;
    *(float2*)(agg + ((size_t)b * N_ + node) * 128 + col0) = o;
  }
}

// ---------------------------------------------------------------------------
// K4: y = agg @ Wo + bo (MFMA); h = x + y; LayerNorm(h) -> out
// ---------------------------------------------------------------------------
__global__ __launch_bounds__(256) void out_ln_mfma(
    const float* __restrict__ agg, const short* __restrict__ wto,
    const float* __restrict__ bo, const float* __restrict__ x,
    const float* __restrict__ lng, const float* __restrict__ lnb,
    float* __restrict__ out) {
  __shared__ short as_[64][136];
  const int tid  = threadIdx.x;
  const int lane = tid & 63;
  const int wave = tid >> 6;
  const int ln15 = lane & 15;
  const int g    = lane >> 4;
  const long rowBase = (long)blockIdx.x * 64;

  for (int i = tid; i < 64 * 32; i += 256) {
    const int r  = i >> 5;
    const int c4 = (i & 31) * 4;
    const float4 v = *(const float4*)(agg + (rowBase + r) * 128 + c4);
    short4v sv; sv.x = bfb(v.x); sv.y = bfb(v.y); sv.z = bfb(v.z); sv.w = bfb(v.w);
    *(short4v*)&as_[r][c4] = sv;
  }
  __syncthreads();

  short8v af[4];
#pragma unroll
  for (int kk = 0; kk < 4; ++kk)
    af[kk] = *(const short8v*)&as_[wave * 16 + ln15][kk * 32 + g * 8];

  f32x4 acc[8];
#pragma unroll
  for (int cb = 0; cb < 8; ++cb) acc[cb] = (f32x4){0.f, 0.f, 0.f, 0.f};

#pragma unroll
  for (int kk = 0; kk < 4; ++kk) {
#pragma unroll
    for (int cb = 0; cb < 8; ++cb) {
      const short8v bfr =
          *(const short8v*)(wto + (cb * 16 + ln15) * 128 + kk * 32 + g * 8);
      acc[cb] = __builtin_amdgcn_mfma_f32_16x16x32_bf16(af[kk], bfr, acc[cb], 0, 0, 0);
    }
  }

#pragma unroll
  for (int cb = 0; cb < 8; ++cb) {
    const int col = cb * 16 + ln15;
    const float bov = bo[col];
#pragma unroll
    for (int r = 0; r < 4; ++r) {
      const long row = rowBase + wave * 16 + g * 4 + r;
      acc[cb][r] += bov + x[row * 128 + col];
    }
  }

  float s1[4], s2[4];
#pragma unroll
  for (int r = 0; r < 4; ++r) {
    s1[r] = 0.f; s2[r] = 0.f;
#pragma unroll
    for (int cb = 0; cb < 8; ++cb) {
      s1[r] += acc[cb][r];
      s2[r] = fmaf(acc[cb][r], acc[cb][r], s2[r]);
    }
  }
#pragma unroll
  for (int m = 1; m < 16; m <<= 1) {
#pragma unroll
    for (int r = 0; r < 4; ++r) {
      s1[r] += __shfl_xor(s1[r], m);
      s2[r] += __shfl_xor(s2[r], m);
    }
  }
  float mu[4], inv[4];
#pragma unroll
  for (int r = 0; r < 4; ++r) {
    mu[r] = s1[r] * (1.f / 128.f);
    const float var = s2[r] * (1.f / 128.f) - mu[r] * mu[r];
    inv[r] = rsqrtf(var + 1e-5f);
  }

#pragma unroll
  for (int cb = 0; cb < 8; ++cb) {
    const int col = cb * 16 + ln15;
    const float gv = lng[col], bv_ = lnb[col];
#pragma unroll
    for (int r = 0; r < 4; ++r) {
      const long row = rowBase + wave * 16 + g * 4 + r;
      out[row * 128 + col] = (acc[cb][r] - mu[r]) * inv[r] * gv + bv_;
    }
  }
}

// ---------------------------------------------------------------------------
extern "C" void kernel_launch(void* const* d_in, const int* in_sizes, int n_in,
                              void* d_out, int out_size, void* d_ws, size_t ws_size,
                              hipStream_t stream) {
  const float* x   = (const float*)d_in[0];
  const int*   ei  = (const int*)d_in[1];
  const float* ea  = (const float*)d_in[2];
  const float* Wq  = (const float*)d_in[3];
  const float* bq  = (const float*)d_in[4];
  const float* Wk  = (const float*)d_in[5];
  const float* bk  = (const float*)d_in[6];
  const float* Wv  = (const float*)d_in[7];
  const float* bv  = (const float*)d_in[8];
  const float* Wf  = (const float*)d_in[9];
  const float* bf  = (const float*)d_in[10];
  const float* Wo  = (const float*)d_in[11];
  const float* bo  = (const float*)d_in[12];
  const float* lng = (const float*)d_in[13];
  const float* lnb = (const float*)d_in[14];
  float* out = (float*)d_out;

  const size_t NQ = (size_t)B_ * N_ * HID_;  // 5,120,000

  char* base = (char*)d_ws;
  size_t off = 0;
  float* Q    = (float*)(base + off); off += NQ * 4;                 // 20.48MB
  float* agg  = (float*)(base + off); off += NQ * 4;                 // 20.48MB
  float* eas  = (float*)(base + off); off += (size_t)E_ * 16 * 4;    // 10.24MB
  unsigned char* kv8 = (unsigned char*)(base + off);
  off += (size_t)B_ * N_ * 256;                                      // 10.24MB
  short* wt   = (short*)(base + off); off += 4 * 16384 * 2;          // 128KB
  int*  cnt    = (int*)(base + off); off += N_ * 4;
  int*  rowptr = (int*)(base + off); off += (N_ + 1) * 4;
  int*  fill   = (int*)(base + off); off += N_ * 4;
  int*  esrc   = (int*)(base + off); off += E_ * 4;

  hipMemsetAsync(cnt, 0, N_ * sizeof(int), stream);

  wt_prep<<<256, 256, 0, stream>>>(Wq, Wk, Wv, Wo, wt);
  qkv_mfma<<<(B_ * N_) / 64, 256, 0, stream>>>(x, wt, bq, bk, bv, Q, kv8);
  csr_hist<<<(E_ + 255) / 256, 256, 0, stream>>>(ei, cnt);
  csr_scan<<<1, 1024, 0, stream>>>(cnt, rowptr, fill);
  csr_scatter<<<(E_ + 255) / 256, 256, 0, stream>>>(ei, ea, fill, esrc, eas);
  fused_attn<<<PGRID, 256, 0, stream>>>(rowptr, esrc, eas, Wf, bf, Q, kv8, agg);
  out_ln_mfma<<<(B_ * N_) / 64, 256, 0, stream>>>(agg, wt + 3 * 16384, bo, x, lng, lnb, out);
}

// Round 15
// 181.697 us; speedup vs baseline: 1.3041x; 1.1524x over previous
//
#include <hip/hip_runtime.h>
#include <hip/hip_bf16.h>

#define B_ 4
#define N_ 10000
#define E_ 160000
#define D_ 128
#define H_ 4
#define HID_ 128
#define DK_ 32
#define DE_ 16
#define PGRID 2048

typedef __attribute__((ext_vector_type(8))) short short8v;
typedef __attribute__((ext_vector_type(4))) short short4v;
typedef __attribute__((ext_vector_type(4))) float f32x4;
typedef __attribute__((ext_vector_type(2))) float f32x2;

// fp32 -> bf16 bits, round-to-nearest-even
__device__ __forceinline__ short bfb(float f) {
  union { float f; unsigned u; } c; c.f = f;
  unsigned u = c.u + 0x7FFFu + ((c.u >> 16) & 1u);
  return (short)(u >> 16);
}

// fp32 -> fp8 e4m3 (OCP on gfx950)
__device__ __forceinline__ unsigned char f2fp8(float f) {
  int r = __builtin_amdgcn_cvt_pk_fp8_f32(f, f, 0, false);
  return (unsigned char)(r & 0xff);
}
// dword of 4 fp8 -> 2+2 fp32
__device__ __forceinline__ f32x2 fp8lo(unsigned u) {
  return __builtin_amdgcn_cvt_pk_f32_fp8((int)u, false);
}
__device__ __forceinline__ f32x2 fp8hi(unsigned u) {
  return __builtin_amdgcn_cvt_pk_f32_fp8((int)u, true);
}

// ---------------------------------------------------------------------------
// P0: W^T bf16 prep. wt[m][n][k] = bf16(W_m[k*128+n]),  m: 0=q 1=k 2=v 3=o
// ---------------------------------------------------------------------------
__global__ __launch_bounds__(256) void wt_prep(
    const float* __restrict__ Wq, const float* __restrict__ Wk,
    const float* __restrict__ Wv, const float* __restrict__ Wo,
    short* __restrict__ wt) {
  const float* Ws[4] = {Wq, Wk, Wv, Wo};
  const int i = blockIdx.x * 256 + threadIdx.x;   // 0..65535
  const int m = i >> 14;
  const int k = (i >> 7) & 127;
  const int n = i & 127;
  wt[(size_t)m * 16384 + n * 128 + k] = bfb(Ws[m][k * 128 + n]);
}

// ---------------------------------------------------------------------------
// K1: QKV projection via MFMA. block = 256 (4 waves), 64 rows/block.
// Q -> fp32 [b][n][128]; K,V -> fp8 e4m3 kv8[n][b][0:128 = K | 128:256 = V]
// ---------------------------------------------------------------------------
__global__ __launch_bounds__(256) void qkv_mfma(
    const float* __restrict__ x, const short* __restrict__ wt,
    const float* __restrict__ bq, const float* __restrict__ bk,
    const float* __restrict__ bv,
    float* __restrict__ Q, unsigned char* __restrict__ kv8) {
  __shared__ short xs[64][136];
  const int tid  = threadIdx.x;
  const int lane = tid & 63;
  const int wave = tid >> 6;
  const int ln15 = lane & 15;
  const int g    = lane >> 4;
  const long rowBase = (long)blockIdx.x * 64;

  for (int i = tid; i < 64 * 32; i += 256) {
    const int r  = i >> 5;
    const int c4 = (i & 31) * 4;
    const float4 v = *(const float4*)(x + (rowBase + r) * 128 + c4);
    short4v sv; sv.x = bfb(v.x); sv.y = bfb(v.y); sv.z = bfb(v.z); sv.w = bfb(v.w);
    *(short4v*)&xs[r][c4] = sv;
  }
  __syncthreads();

  short8v af[4];
#pragma unroll
  for (int kk = 0; kk < 4; ++kk)
    af[kk] = *(const short8v*)&xs[wave * 16 + ln15][kk * 32 + g * 8];

  const float* bs[3] = {bq, bk, bv};

  int bbv[4], nnv[4];
#pragma unroll
  for (int r = 0; r < 4; ++r) {
    const long row = rowBase + wave * 16 + g * 4 + r;
    bbv[r] = (int)(row / N_);
    nnv[r] = (int)(row - (long)bbv[r] * N_);
  }

#pragma unroll
  for (int m = 0; m < 3; ++m) {
    const short* Wt = wt + (size_t)m * 16384;
    f32x4 acc[8];
#pragma unroll
    for (int cb = 0; cb < 8; ++cb) acc[cb] = (f32x4){0.f, 0.f, 0.f, 0.f};

#pragma unroll
    for (int kk = 0; kk < 4; ++kk) {
#pragma unroll
      for (int cb = 0; cb < 8; ++cb) {
        const short8v bfr =
            *(const short8v*)(Wt + (cb * 16 + ln15) * 128 + kk * 32 + g * 8);
        acc[cb] = __builtin_amdgcn_mfma_f32_16x16x32_bf16(af[kk], bfr, acc[cb], 0, 0, 0);
      }
    }

    const float* bias = bs[m];
#pragma unroll
    for (int cb = 0; cb < 8; ++cb) {
      const int col = cb * 16 + ln15;
      const float bv_ = bias[col];
#pragma unroll
      for (int r = 0; r < 4; ++r) {
        const float val = acc[cb][r] + bv_;
        if (m == 0) {
          const long row = rowBase + wave * 16 + g * 4 + r;
          Q[row * 128 + col] = val;
        } else {
          kv8[(((size_t)nnv[r] * 4 + bbv[r]) << 8) + (m - 1) * 128 + col] = f2fp8(val);
        }
      }
    }
  }
}

// ---------------------------------------------------------------------------
// CSR build
// ---------------------------------------------------------------------------
__global__ __launch_bounds__(256) void csr_hist(const int* __restrict__ ei,
                                                int* __restrict__ cnt) {
  const int e = blockIdx.x * 256 + threadIdx.x;
  if (e < E_) atomicAdd(&cnt[ei[E_ + e]], 1);
}

__global__ __launch_bounds__(1024) void csr_scan(const int* __restrict__ cnt,
                                                 int* __restrict__ rowptr,
                                                 int* __restrict__ fill) {
  __shared__ int part[1024];
  const int t = threadIdx.x;
  int local[10];
  int sum = 0;
#pragma unroll
  for (int i = 0; i < 10; ++i) {
    const int idx = t * 10 + i;
    local[i] = sum;
    sum += (idx < N_) ? cnt[idx] : 0;
  }
  part[t] = sum;
  __syncthreads();
  for (int off = 1; off < 1024; off <<= 1) {
    const int v = (t >= off) ? part[t - off] : 0;
    __syncthreads();
    part[t] += v;
    __syncthreads();
  }
  const int excl = (t == 0) ? 0 : part[t - 1];
#pragma unroll
  for (int i = 0; i < 10; ++i) {
    const int idx = t * 10 + i;
    if (idx <= N_) {
      const int o = excl + local[i];
      rowptr[idx] = o;
      if (idx < N_) fill[idx] = o;
    }
  }
}

// scatter: CSR-ordered src + CSR-ordered copy of edge_attr
__global__ __launch_bounds__(256) void csr_scatter(
    const int* __restrict__ ei, const float* __restrict__ ea,
    int* __restrict__ fill, int* __restrict__ esrc, float* __restrict__ eas) {
  const int e = blockIdx.x * 256 + threadIdx.x;
  if (e < E_) {
    const int dst = ei[E_ + e];
    const int pos = atomicAdd(&fill[dst], 1);
    esrc[pos] = ei[e];
    const float4* s4 = (const float4*)(ea + (size_t)e * 16);
    float4* d4 = (float4*)(eas + (size_t)pos * 16);
    d4[0] = s4[0]; d4[1] = s4[1]; d4[2] = s4[2]; d4[3] = s4[3];
  }
}

// ---------------------------------------------------------------------------
// P1: FiLM precompute, fp8 RAW (gamma WITHOUT +1; beta raw).
// film8[i][c] = fp8((eas[i]@Wf + bf)[c]),  c in 0..255 (0:128 gamma, 128:256 beta)
// Persistent grid-stride; wave = edge; lane holds its 4 Wf cols in registers.
// ---------------------------------------------------------------------------
__global__ __launch_bounds__(256) void film_prep(
    const float* __restrict__ eas, const float* __restrict__ Wf,
    const float* __restrict__ bf, unsigned char* __restrict__ film8) {
  const int lane = threadIdx.x & 63;
  const int wave = threadIdx.x >> 6;
  const int c0 = lane * 4;

  float4 w[16];
#pragma unroll
  for (int j = 0; j < 16; ++j) w[j] = *(const float4*)(Wf + j * 256 + c0);
  const float4 bias = *(const float4*)(bf + c0);

  for (int i = blockIdx.x * 4 + wave; i < E_; i += PGRID * 4) {
    const float* ep = eas + (size_t)i * 16;
    const float4 a0 = *(const float4*)ep;
    const float4 a1 = *(const float4*)(ep + 4);
    const float4 a2 = *(const float4*)(ep + 8);
    const float4 a3 = *(const float4*)(ep + 12);
    const float ev[16] = {a0.x,a0.y,a0.z,a0.w, a1.x,a1.y,a1.z,a1.w,
                          a2.x,a2.y,a2.z,a2.w, a3.x,a3.y,a3.z,a3.w};
    float ox = bias.x, oy = bias.y, oz = bias.z, ow = bias.w;
#pragma unroll
    for (int j = 0; j < 16; ++j) {
      ox = fmaf(ev[j], w[j].x, ox);
      oy = fmaf(ev[j], w[j].y, oy);
      oz = fmaf(ev[j], w[j].z, oz);
      ow = fmaf(ev[j], w[j].w, ow);
    }
    int r = __builtin_amdgcn_cvt_pk_fp8_f32(ox, oy, 0, false);
    r = __builtin_amdgcn_cvt_pk_fp8_f32(oz, ow, r, true);
    ((int*)(film8 + (size_t)i * 256))[lane] = r;
  }
}

// ---------------------------------------------------------------------------
// K2: fused logits + softmax + aggregation — ZERO shuffles in the edge loop.
// Persistent: PGRID blocks x 4 waves; wave = node (grid-stride).
// lane = e2*32 + dh*16 + b*4 + h: lane owns 16 dims (half-head dh of head h,
// batch b) for edge-slot e2. q[16] and acc[16] in registers; K/V/gamma/beta
// are single 16B fp8 loads. km = k + fma(k,g,t)  (g = raw gamma, t = beta).
// Logit: in-lane 16-dot + ONE shfl_xor(16) to join dh halves; exp per-lane.
// End of node: acc/se joined over e2 via shfl_xor(32); e2==0 lanes write.
// Single-pass softmax (no max): logits are O(0.05).
// ---------------------------------------------------------------------------
__global__ __launch_bounds__(256) void fused_attn(
    const int* __restrict__ rowptr, const int* __restrict__ esrc,
    const unsigned char* __restrict__ film8, const float* __restrict__ Q,
    const unsigned char* __restrict__ kv8, float* __restrict__ agg) {
  const int wave = threadIdx.x >> 6;
  const int lane = threadIdx.x & 63;
  const int e2 = lane >> 5;
  const int dh = (lane >> 4) & 1;
  const int b  = (lane >> 2) & 3;
  const int h  = lane & 3;
  const int col0 = h * 32 + dh * 16;

  for (int node = blockIdx.x * 4 + wave; node < N_; node += PGRID * 4) {
    const int beg = rowptr[node], end = rowptr[node + 1];

    float q[16];
    {
      const float* qp = Q + ((size_t)b * N_ + node) * 128 + col0;
#pragma unroll
      for (int c = 0; c < 4; ++c) {
        const float4 t = *(const float4*)(qp + c * 4);
        q[c*4+0] = t.x; q[c*4+1] = t.y; q[c*4+2] = t.z; q[c*4+3] = t.w;
      }
    }
    float acc[16];
#pragma unroll
    for (int d = 0; d < 16; ++d) acc[d] = 0.f;
    float se = 0.f;

    for (int i0 = beg; i0 < end; i0 += 2) {
      const int ii = i0 + e2;
      const bool valid = ii < end;
      const int ic = valid ? ii : i0;
      const int src = esrc[ic];
      const unsigned char* kp = kv8 + ((((size_t)src << 2) + b) << 8) + col0;
      const unsigned char* fp = film8 + (size_t)ic * 256 + col0;
      const uint4 kw = *(const uint4*)kp;
      const uint4 vw = *(const uint4*)(kp + 128);
      const uint4 gw = *(const uint4*)fp;
      const uint4 tw = *(const uint4*)(fp + 128);
      const unsigned ks[4] = {kw.x, kw.y, kw.z, kw.w};
      const unsigned vs[4] = {vw.x, vw.y, vw.z, vw.w};
      const unsigned gs[4] = {gw.x, gw.y, gw.z, gw.w};
      const unsigned ts[4] = {tw.x, tw.y, tw.z, tw.w};

      float pacc[4] = {0.f, 0.f, 0.f, 0.f};
#pragma unroll
      for (int w = 0; w < 4; ++w) {
        const f32x2 k0 = fp8lo(ks[w]), k1 = fp8hi(ks[w]);
        const f32x2 g0 = fp8lo(gs[w]), g1 = fp8hi(gs[w]);
        const f32x2 t0 = fp8lo(ts[w]), t1 = fp8hi(ts[w]);
        float km;
        km = k0.x + fmaf(k0.x, g0.x, t0.x); pacc[w] = fmaf(q[4*w+0], km, pacc[w]);
        km = k0.y + fmaf(k0.y, g0.y, t0.y); pacc[w] = fmaf(q[4*w+1], km, pacc[w]);
        km = k1.x + fmaf(k1.x, g1.x, t1.x); pacc[w] = fmaf(q[4*w+2], km, pacc[w]);
        km = k1.y + fmaf(k1.y, g1.y, t1.y); pacc[w] = fmaf(q[4*w+3], km, pacc[w]);
      }
      float pl = (pacc[0] + pacc[1]) + (pacc[2] + pacc[3]);
      pl += __shfl_xor(pl, 16);   // join dh halves -> full 32-dim logit

      float ex = __expf(pl * 0.17677669529663687f);  // 1/sqrt(32)
      ex = valid ? ex : 0.f;
      se += ex;
#pragma unroll
      for (int w = 0; w < 4; ++w) {
        const f32x2 v0 = fp8lo(vs[w]), v1 = fp8hi(vs[w]);
        acc[4*w+0] = fmaf(ex, v0.x, acc[4*w+0]);
        acc[4*w+1] = fmaf(ex, v0.y, acc[4*w+1]);
        acc[4*w+2] = fmaf(ex, v1.x, acc[4*w+2]);
        acc[4*w+3] = fmaf(ex, v1.y, acc[4*w+3]);
      }
    }

    // join the two e2 slots
#pragma unroll
    for (int d = 0; d < 16; ++d) acc[d] += __shfl_xor(acc[d], 32);
    se += __shfl_xor(se, 32);

    if (e2 == 0) {
      const float inv = (end > beg) ? 1.f / se : 0.f;
      float* ap = agg + ((size_t)b * N_ + node) * 128 + col0;
#pragma unroll
      for (int c = 0; c < 4; ++c) {
        float4 o;
        o.x = acc[c*4+0] * inv; o.y = acc[c*4+1] * inv;
        o.z = acc[c*4+2] * inv; o.w = acc[c*4+3] * inv;
        *(float4*)(ap + c * 4) = o;
      }
    }
  }
}

// ---------------------------------------------------------------------------
// K4: y = agg @ Wo + bo (MFMA); h = x + y; LayerNorm(h) -> out
// ---------------------------------------------------------------------------
__global__ __launch_bounds__(256) void out_ln_mfma(
    const float* __restrict__ agg, const short* __restrict__ wto,
    const float* __restrict__ bo, const float* __restrict__ x,
    const float* __restrict__ lng, const float* __restrict__ lnb,
    float* __restrict__ out) {
  __shared__ short as_[64][136];
  const int tid  = threadIdx.x;
  const int lane = tid & 63;
  const int wave = tid >> 6;
  const int ln15 = lane & 15;
  const int g    = lane >> 4;
  const long rowBase = (long)blockIdx.x * 64;

  for (int i = tid; i < 64 * 32; i += 256) {
    const int r  = i >> 5;
    const int c4 = (i & 31) * 4;
    const float4 v = *(const float4*)(agg + (rowBase + r) * 128 + c4);
    short4v sv; sv.x = bfb(v.x); sv.y = bfb(v.y); sv.z = bfb(v.z); sv.w = bfb(v.w);
    *(short4v*)&as_[r][c4] = sv;
  }
  __syncthreads();

  short8v af[4];
#pragma unroll
  for (int kk = 0; kk < 4; ++kk)
    af[kk] = *(const short8v*)&as_[wave * 16 + ln15][kk * 32 + g * 8];

  f32x4 acc[8];
#pragma unroll
  for (int cb = 0; cb < 8; ++cb) acc[cb] = (f32x4){0.f, 0.f, 0.f, 0.f};

#pragma unroll
  for (int kk = 0; kk < 4; ++kk) {
#pragma unroll
    for (int cb = 0; cb < 8; ++cb) {
      const short8v bfr =
          *(const short8v*)(wto + (cb * 16 + ln15) * 128 + kk * 32 + g * 8);
      acc[cb] = __builtin_amdgcn_mfma_f32_16x16x32_bf16(af[kk], bfr, acc[cb], 0, 0, 0);
    }
  }

#pragma unroll
  for (int cb = 0; cb < 8; ++cb) {
    const int col = cb * 16 + ln15;
    const float bov = bo[col];
#pragma unroll
    for (int r = 0; r < 4; ++r) {
      const long row = rowBase + wave * 16 + g * 4 + r;
      acc[cb][r] += bov + x[row * 128 + col];
    }
  }

  float s1[4], s2[4];
#pragma unroll
  for (int r = 0; r < 4; ++r) {
    s1[r] = 0.f; s2[r] = 0.f;
#pragma unroll
    for (int cb = 0; cb < 8; ++cb) {
      s1[r] += acc[cb][r];
      s2[r] = fmaf(acc[cb][r], acc[cb][r], s2[r]);
    }
  }
#pragma unroll
  for (int m = 1; m < 16; m <<= 1) {
#pragma unroll
    for (int r = 0; r < 4; ++r) {
      s1[r] += __shfl_xor(s1[r], m);
      s2[r] += __shfl_xor(s2[r], m);
    }
  }
  float mu[4], inv[4];
#pragma unroll
  for (int r = 0; r < 4; ++r) {
    mu[r] = s1[r] * (1.f / 128.f);
    const float var = s2[r] * (1.f / 128.f) - mu[r] * mu[r];
    inv[r] = rsqrtf(var + 1e-5f);
  }

#pragma unroll
  for (int cb = 0; cb < 8; ++cb) {
    const int col = cb * 16 + ln15;
    const float gv = lng[col], bv_ = lnb[col];
#pragma unroll
    for (int r = 0; r < 4; ++r) {
      const long row = rowBase + wave * 16 + g * 4 + r;
      out[row * 128 + col] = (acc[cb][r] - mu[r]) * inv[r] * gv + bv_;
    }
  }
}

// ---------------------------------------------------------------------------
extern "C" void kernel_launch(void* const* d_in, const int* in_sizes, int n_in,
                              void* d_out, int out_size, void* d_ws, size_t ws_size,
                              hipStream_t stream) {
  const float* x   = (const float*)d_in[0];
  const int*   ei  = (const int*)d_in[1];
  const float* ea  = (const float*)d_in[2];
  const float* Wq  = (const float*)d_in[3];
  const float* bq  = (const float*)d_in[4];
  const float* Wk  = (const float*)d_in[5];
  const float* bk  = (const float*)d_in[6];
  const float* Wv  = (const float*)d_in[7];
  const float* bv  = (const float*)d_in[8];
  const float* Wf  = (const float*)d_in[9];
  const float* bf  = (const float*)d_in[10];
  const float* Wo  = (const float*)d_in[11];
  const float* bo  = (const float*)d_in[12];
  const float* lng = (const float*)d_in[13];
  const float* lnb = (const float*)d_in[14];
  float* out = (float*)d_out;

  const size_t NQ = (size_t)B_ * N_ * HID_;  // 5,120,000

  char* base = (char*)d_ws;
  size_t off = 0;
  float* Q    = (float*)(base + off); off += NQ * 4;                 // 20.48MB
  float* agg  = (float*)(base + off); off += NQ * 4;                 // 20.48MB
  float* eas  = (float*)(base + off); off += (size_t)E_ * 16 * 4;    // 10.24MB
  unsigned char* kv8 = (unsigned char*)(base + off);
  off += (size_t)B_ * N_ * 256;                                      // 10.24MB
  unsigned char* film8 = (unsigned char*)(base + off);
  off += (size_t)E_ * 256;                                           // 40.96MB
  short* wt   = (short*)(base + off); off += 4 * 16384 * 2;          // 128KB
  int*  cnt    = (int*)(base + off); off += N_ * 4;
  int*  rowptr = (int*)(base + off); off += (N_ + 1) * 4;
  int*  fill   = (int*)(base + off); off += N_ * 4;
  int*  esrc   = (int*)(base + off); off += E_ * 4;

  hipMemsetAsync(cnt, 0, N_ * sizeof(int), stream);

  wt_prep<<<256, 256, 0, stream>>>(Wq, Wk, Wv, Wo, wt);
  qkv_mfma<<<(B_ * N_) / 64, 256, 0, stream>>>(x, wt, bq, bk, bv, Q, kv8);
  csr_hist<<<(E_ + 255) / 256, 256, 0, stream>>>(ei, cnt);
  csr_scan<<<1, 1024, 0, stream>>>(cnt, rowptr, fill);
  csr_scatter<<<(E_ + 255) / 256, 256, 0, stream>>>(ei, ea, fill, esrc, eas);
  film_prep<<<PGRID, 256, 0, stream>>>(eas, Wf, bf, film8);
  fused_attn<<<PGRID, 256, 0, stream>>>(rowptr, esrc, film8, Q, kv8, agg);
  out_ln_mfma<<<(B_ * N_) / 64, 256, 0, stream>>>(agg, wt + 3 * 16384, bo, x, lng, lnb, out);
}

// Round 16
// 175.221 us; speedup vs baseline: 1.3523x; 1.0370x over previous
//
#include <hip/hip_runtime.h>
#include <hip/hip_bf16.h>

#define B_ 4
#define N_ 10000
#define E_ 160000
#define D_ 128
#define H_ 4
#define HID_ 128
#define DK_ 32
#define DE_ 16
#define PGRID 2048

typedef __attribute__((ext_vector_type(8))) short short8v;
typedef __attribute__((ext_vector_type(4))) short short4v;
typedef __attribute__((ext_vector_type(4))) float f32x4;
typedef __attribute__((ext_vector_type(2))) float f32x2;

// fp32 -> bf16 bits, round-to-nearest-even
__device__ __forceinline__ short bfb(float f) {
  union { float f; unsigned u; } c; c.f = f;
  unsigned u = c.u + 0x7FFFu + ((c.u >> 16) & 1u);
  return (short)(u >> 16);
}

// fp32 -> fp8 e4m3 (OCP on gfx950)
__device__ __forceinline__ unsigned char f2fp8(float f) {
  int r = __builtin_amdgcn_cvt_pk_fp8_f32(f, f, 0, false);
  return (unsigned char)(r & 0xff);
}
// dword of 4 fp8 -> 2+2 fp32
__device__ __forceinline__ f32x2 fp8lo(unsigned u) {
  return __builtin_amdgcn_cvt_pk_f32_fp8((int)u, false);
}
__device__ __forceinline__ f32x2 fp8hi(unsigned u) {
  return __builtin_amdgcn_cvt_pk_f32_fp8((int)u, true);
}

// ---------------------------------------------------------------------------
// P0: W^T bf16 prep. wt[m][n][k] = bf16(W_m[k*128+n]),  m: 0=q 1=k 2=v 3=o
// ---------------------------------------------------------------------------
__global__ __launch_bounds__(256) void wt_prep(
    const float* __restrict__ Wq, const float* __restrict__ Wk,
    const float* __restrict__ Wv, const float* __restrict__ Wo,
    short* __restrict__ wt) {
  const float* Ws[4] = {Wq, Wk, Wv, Wo};
  const int i = blockIdx.x * 256 + threadIdx.x;   // 0..65535
  const int m = i >> 14;
  const int k = (i >> 7) & 127;
  const int n = i & 127;
  wt[(size_t)m * 16384 + n * 128 + k] = bfb(Ws[m][k * 128 + n]);
}

// ---------------------------------------------------------------------------
// K1: QKV projection via MFMA. ONE WAVE per block, 16 rows/block, grid 2500.
// (was 4-wave/64-row blocks at grid 625 -> only ~10 waves/CU; 1-wave blocks
// give 4x the schedulable units for latency hiding.)
// Q -> fp32 [b][n][128]; K,V -> fp8 e4m3 kv8[n][b][0:128 = K | 128:256 = V]
// ---------------------------------------------------------------------------
__global__ __launch_bounds__(64) void qkv_mfma(
    const float* __restrict__ x, const short* __restrict__ wt,
    const float* __restrict__ bq, const float* __restrict__ bk,
    const float* __restrict__ bv,
    float* __restrict__ Q, unsigned char* __restrict__ kv8) {
  __shared__ short xs[16][136];
  const int lane = threadIdx.x;
  const int ln15 = lane & 15;
  const int g    = lane >> 4;
  const long rowBase = (long)blockIdx.x * 16;

  for (int i = lane; i < 16 * 32; i += 64) {
    const int r  = i >> 5;
    const int c4 = (i & 31) * 4;
    const float4 v = *(const float4*)(x + (rowBase + r) * 128 + c4);
    short4v sv; sv.x = bfb(v.x); sv.y = bfb(v.y); sv.z = bfb(v.z); sv.w = bfb(v.w);
    *(short4v*)&xs[r][c4] = sv;
  }
  __syncthreads();

  short8v af[4];
#pragma unroll
  for (int kk = 0; kk < 4; ++kk)
    af[kk] = *(const short8v*)&xs[ln15][kk * 32 + g * 8];

  const float* bs[3] = {bq, bk, bv};

  int bbv[4], nnv[4];
#pragma unroll
  for (int r = 0; r < 4; ++r) {
    const long row = rowBase + g * 4 + r;
    bbv[r] = (int)(row / N_);
    nnv[r] = (int)(row - (long)bbv[r] * N_);
  }

#pragma unroll
  for (int m = 0; m < 3; ++m) {
    const short* Wt = wt + (size_t)m * 16384;
    f32x4 acc[8];
#pragma unroll
    for (int cb = 0; cb < 8; ++cb) acc[cb] = (f32x4){0.f, 0.f, 0.f, 0.f};

#pragma unroll
    for (int kk = 0; kk < 4; ++kk) {
#pragma unroll
      for (int cb = 0; cb < 8; ++cb) {
        const short8v bfr =
            *(const short8v*)(Wt + (cb * 16 + ln15) * 128 + kk * 32 + g * 8);
        acc[cb] = __builtin_amdgcn_mfma_f32_16x16x32_bf16(af[kk], bfr, acc[cb], 0, 0, 0);
      }
    }

    const float* bias = bs[m];
#pragma unroll
    for (int cb = 0; cb < 8; ++cb) {
      const int col = cb * 16 + ln15;
      const float bv_ = bias[col];
#pragma unroll
      for (int r = 0; r < 4; ++r) {
        const float val = acc[cb][r] + bv_;
        if (m == 0) {
          const long row = rowBase + g * 4 + r;
          Q[row * 128 + col] = val;
        } else {
          kv8[(((size_t)nnv[r] * 4 + bbv[r]) << 8) + (m - 1) * 128 + col] = f2fp8(val);
        }
      }
    }
  }
}

// ---------------------------------------------------------------------------
// CSR build
// ---------------------------------------------------------------------------
__global__ __launch_bounds__(256) void csr_hist(const int* __restrict__ ei,
                                                int* __restrict__ cnt) {
  const int e = blockIdx.x * 256 + threadIdx.x;
  if (e < E_) atomicAdd(&cnt[ei[E_ + e]], 1);
}

__global__ __launch_bounds__(1024) void csr_scan(const int* __restrict__ cnt,
                                                 int* __restrict__ rowptr,
                                                 int* __restrict__ fill) {
  __shared__ int part[1024];
  const int t = threadIdx.x;
  int local[10];
  int sum = 0;
#pragma unroll
  for (int i = 0; i < 10; ++i) {
    const int idx = t * 10 + i;
    local[i] = sum;
    sum += (idx < N_) ? cnt[idx] : 0;
  }
  part[t] = sum;
  __syncthreads();
  for (int off = 1; off < 1024; off <<= 1) {
    const int v = (t >= off) ? part[t - off] : 0;
    __syncthreads();
    part[t] += v;
    __syncthreads();
  }
  const int excl = (t == 0) ? 0 : part[t - 1];
#pragma unroll
  for (int i = 0; i < 10; ++i) {
    const int idx = t * 10 + i;
    if (idx <= N_) {
      const int o = excl + local[i];
      rowptr[idx] = o;
      if (idx < N_) fill[idx] = o;
    }
  }
}

// scatter: CSR-ordered src + CSR-ordered copy of edge_attr
__global__ __launch_bounds__(256) void csr_scatter(
    const int* __restrict__ ei, const float* __restrict__ ea,
    int* __restrict__ fill, int* __restrict__ esrc, float* __restrict__ eas) {
  const int e = blockIdx.x * 256 + threadIdx.x;
  if (e < E_) {
    const int dst = ei[E_ + e];
    const int pos = atomicAdd(&fill[dst], 1);
    esrc[pos] = ei[e];
    const float4* s4 = (const float4*)(ea + (size_t)e * 16);
    float4* d4 = (float4*)(eas + (size_t)pos * 16);
    d4[0] = s4[0]; d4[1] = s4[1]; d4[2] = s4[2]; d4[3] = s4[3];
  }
}

// ---------------------------------------------------------------------------
// P1: FiLM precompute, fp8 RAW (gamma WITHOUT +1; beta raw).
// film8[i][c] = fp8((eas[i]@Wf + bf)[c]),  c in 0..255 (0:128 gamma, 128:256 beta)
// Persistent grid-stride; wave = edge; lane holds its 4 Wf cols in registers.
// ---------------------------------------------------------------------------
__global__ __launch_bounds__(256) void film_prep(
    const float* __restrict__ eas, const float* __restrict__ Wf,
    const float* __restrict__ bf, unsigned char* __restrict__ film8) {
  const int lane = threadIdx.x & 63;
  const int wave = threadIdx.x >> 6;
  const int c0 = lane * 4;

  float4 w[16];
#pragma unroll
  for (int j = 0; j < 16; ++j) w[j] = *(const float4*)(Wf + j * 256 + c0);
  const float4 bias = *(const float4*)(bf + c0);

  for (int i = blockIdx.x * 4 + wave; i < E_; i += PGRID * 4) {
    const float* ep = eas + (size_t)i * 16;
    const float4 a0 = *(const float4*)ep;
    const float4 a1 = *(const float4*)(ep + 4);
    const float4 a2 = *(const float4*)(ep + 8);
    const float4 a3 = *(const float4*)(ep + 12);
    const float ev[16] = {a0.x,a0.y,a0.z,a0.w, a1.x,a1.y,a1.z,a1.w,
                          a2.x,a2.y,a2.z,a2.w, a3.x,a3.y,a3.z,a3.w};
    float ox = bias.x, oy = bias.y, oz = bias.z, ow = bias.w;
#pragma unroll
    for (int j = 0; j < 16; ++j) {
      ox = fmaf(ev[j], w[j].x, ox);
      oy = fmaf(ev[j], w[j].y, oy);
      oz = fmaf(ev[j], w[j].z, oz);
      ow = fmaf(ev[j], w[j].w, ow);
    }
    int r = __builtin_amdgcn_cvt_pk_fp8_f32(ox, oy, 0, false);
    r = __builtin_amdgcn_cvt_pk_fp8_f32(oz, ow, r, true);
    ((int*)(film8 + (size_t)i * 256))[lane] = r;
  }
}

// ---------------------------------------------------------------------------
// K2: fused logits + softmax + aggregation — ZERO shuffles in the edge loop.
// Persistent: PGRID blocks x 4 waves; wave = node (grid-stride).
// lane = e2*32 + dh*16 + b*4 + h: lane owns 16 dims (half-head dh of head h,
// batch b) for edge-slot e2. q[16] and acc[16] in registers; K/V/gamma/beta
// are single 16B fp8 loads. km = k + fma(k,g,t)  (g = raw gamma, t = beta).
// Logit: in-lane 16-dot + ONE shfl_xor(16) to join dh halves; exp per-lane.
// End of node: acc/se joined over e2 via shfl_xor(32); e2==0 lanes write.
// Single-pass softmax (no max): logits are O(0.05).
// ---------------------------------------------------------------------------
__global__ __launch_bounds__(256) void fused_attn(
    const int* __restrict__ rowptr, const int* __restrict__ esrc,
    const unsigned char* __restrict__ film8, const float* __restrict__ Q,
    const unsigned char* __restrict__ kv8, float* __restrict__ agg) {
  const int wave = threadIdx.x >> 6;
  const int lane = threadIdx.x & 63;
  const int e2 = lane >> 5;
  const int dh = (lane >> 4) & 1;
  const int b  = (lane >> 2) & 3;
  const int h  = lane & 3;
  const int col0 = h * 32 + dh * 16;

  for (int node = blockIdx.x * 4 + wave; node < N_; node += PGRID * 4) {
    const int beg = rowptr[node], end = rowptr[node + 1];

    float q[16];
    {
      const float* qp = Q + ((size_t)b * N_ + node) * 128 + col0;
#pragma unroll
      for (int c = 0; c < 4; ++c) {
        const float4 t = *(const float4*)(qp + c * 4);
        q[c*4+0] = t.x; q[c*4+1] = t.y; q[c*4+2] = t.z; q[c*4+3] = t.w;
      }
    }
    float acc[16];
#pragma unroll
    for (int d = 0; d < 16; ++d) acc[d] = 0.f;
    float se = 0.f;

    for (int i0 = beg; i0 < end; i0 += 2) {
      const int ii = i0 + e2;
      const bool valid = ii < end;
      const int ic = valid ? ii : i0;
      const int src = esrc[ic];
      const unsigned char* kp = kv8 + ((((size_t)src << 2) + b) << 8) + col0;
      const unsigned char* fp = film8 + (size_t)ic * 256 + col0;
      const uint4 kw = *(const uint4*)kp;
      const uint4 vw = *(const uint4*)(kp + 128);
      const uint4 gw = *(const uint4*)fp;
      const uint4 tw = *(const uint4*)(fp + 128);
      const unsigned ks[4] = {kw.x, kw.y, kw.z, kw.w};
      const unsigned vs[4] = {vw.x, vw.y, vw.z, vw.w};
      const unsigned gs[4] = {gw.x, gw.y, gw.z, gw.w};
      const unsigned ts[4] = {tw.x, tw.y, tw.z, tw.w};

      float pacc[4] = {0.f, 0.f, 0.f, 0.f};
#pragma unroll
      for (int w = 0; w < 4; ++w) {
        const f32x2 k0 = fp8lo(ks[w]), k1 = fp8hi(ks[w]);
        const f32x2 g0 = fp8lo(gs[w]), g1 = fp8hi(gs[w]);
        const f32x2 t0 = fp8lo(ts[w]), t1 = fp8hi(ts[w]);
        float km;
        km = k0.x + fmaf(k0.x, g0.x, t0.x); pacc[w] = fmaf(q[4*w+0], km, pacc[w]);
        km = k0.y + fmaf(k0.y, g0.y, t0.y); pacc[w] = fmaf(q[4*w+1], km, pacc[w]);
        km = k1.x + fmaf(k1.x, g1.x, t1.x); pacc[w] = fmaf(q[4*w+2], km, pacc[w]);
        km = k1.y + fmaf(k1.y, g1.y, t1.y); pacc[w] = fmaf(q[4*w+3], km, pacc[w]);
      }
      float pl = (pacc[0] + pacc[1]) + (pacc[2] + pacc[3]);
      pl += __shfl_xor(pl, 16);   // join dh halves -> full 32-dim logit

      float ex = __expf(pl * 0.17677669529663687f);  // 1/sqrt(32)
      ex = valid ? ex : 0.f;
      se += ex;
#pragma unroll
      for (int w = 0; w < 4; ++w) {
        const f32x2 v0 = fp8lo(vs[w]), v1 = fp8hi(vs[w]);
        acc[4*w+0] = fmaf(ex, v0.x, acc[4*w+0]);
        acc[4*w+1] = fmaf(ex, v0.y, acc[4*w+1]);
        acc[4*w+2] = fmaf(ex, v1.x, acc[4*w+2]);
        acc[4*w+3] = fmaf(ex, v1.y, acc[4*w+3]);
      }
    }

    // join the two e2 slots
#pragma unroll
    for (int d = 0; d < 16; ++d) acc[d] += __shfl_xor(acc[d], 32);
    se += __shfl_xor(se, 32);

    if (e2 == 0) {
      const float inv = (end > beg) ? 1.f / se : 0.f;
      float* ap = agg + ((size_t)b * N_ + node) * 128 + col0;
#pragma unroll
      for (int c = 0; c < 4; ++c) {
        float4 o;
        o.x = acc[c*4+0] * inv; o.y = acc[c*4+1] * inv;
        o.z = acc[c*4+2] * inv; o.w = acc[c*4+3] * inv;
        *(float4*)(ap + c * 4) = o;
      }
    }
  }
}

// ---------------------------------------------------------------------------
// K4: y = agg @ Wo + bo (MFMA); h = x + y; LayerNorm(h) -> out
// ONE WAVE per block, 16 rows/block, grid 2500 (same restructure as K1).
// ---------------------------------------------------------------------------
__global__ __launch_bounds__(64) void out_ln_mfma(
    const float* __restrict__ agg, const short* __restrict__ wto,
    const float* __restrict__ bo, const float* __restrict__ x,
    const float* __restrict__ lng, const float* __restrict__ lnb,
    float* __restrict__ out) {
  __shared__ short as_[16][136];
  const int lane = threadIdx.x;
  const int ln15 = lane & 15;
  const int g    = lane >> 4;
  const long rowBase = (long)blockIdx.x * 16;

  for (int i = lane; i < 16 * 32; i += 64) {
    const int r  = i >> 5;
    const int c4 = (i & 31) * 4;
    const float4 v = *(const float4*)(agg + (rowBase + r) * 128 + c4);
    short4v sv; sv.x = bfb(v.x); sv.y = bfb(v.y); sv.z = bfb(v.z); sv.w = bfb(v.w);
    *(short4v*)&as_[r][c4] = sv;
  }
  __syncthreads();

  short8v af[4];
#pragma unroll
  for (int kk = 0; kk < 4; ++kk)
    af[kk] = *(const short8v*)&as_[ln15][kk * 32 + g * 8];

  f32x4 acc[8];
#pragma unroll
  for (int cb = 0; cb < 8; ++cb) acc[cb] = (f32x4){0.f, 0.f, 0.f, 0.f};

#pragma unroll
  for (int kk = 0; kk < 4; ++kk) {
#pragma unroll
    for (int cb = 0; cb < 8; ++cb) {
      const short8v bfr =
          *(const short8v*)(wto + (cb * 16 + ln15) * 128 + kk * 32 + g * 8);
      acc[cb] = __builtin_amdgcn_mfma_f32_16x16x32_bf16(af[kk], bfr, acc[cb], 0, 0, 0);
    }
  }

#pragma unroll
  for (int cb = 0; cb < 8; ++cb) {
    const int col = cb * 16 + ln15;
    const float bov = bo[col];
#pragma unroll
    for (int r = 0; r < 4; ++r) {
      const long row = rowBase + g * 4 + r;
      acc[cb][r] += bov + x[row * 128 + col];
    }
  }

  float s1[4], s2[4];
#pragma unroll
  for (int r = 0; r < 4; ++r) {
    s1[r] = 0.f; s2[r] = 0.f;
#pragma unroll
    for (int cb = 0; cb < 8; ++cb) {
      s1[r] += acc[cb][r];
      s2[r] = fmaf(acc[cb][r], acc[cb][r], s2[r]);
    }
  }
#pragma unroll
  for (int m = 1; m < 16; m <<= 1) {
#pragma unroll
    for (int r = 0; r < 4; ++r) {
      s1[r] += __shfl_xor(s1[r], m);
      s2[r] += __shfl_xor(s2[r], m);
    }
  }
  float mu[4], inv[4];
#pragma unroll
  for (int r = 0; r < 4; ++r) {
    mu[r] = s1[r] * (1.f / 128.f);
    const float var = s2[r] * (1.f / 128.f) - mu[r] * mu[r];
    inv[r] = rsqrtf(var + 1e-5f);
  }

#pragma unroll
  for (int cb = 0; cb < 8; ++cb) {
    const int col = cb * 16 + ln15;
    const float gv = lng[col], bv_ = lnb[col];
#pragma unroll
    for (int r = 0; r < 4; ++r) {
      const long row = rowBase + g * 4 + r;
      out[row * 128 + col] = (acc[cb][r] - mu[r]) * inv[r] * gv + bv_;
    }
  }
}

// ---------------------------------------------------------------------------
extern "C" void kernel_launch(void* const* d_in, const int* in_sizes, int n_in,
                              void* d_out, int out_size, void* d_ws, size_t ws_size,
                              hipStream_t stream) {
  const float* x   = (const float*)d_in[0];
  const int*   ei  = (const int*)d_in[1];
  const float* ea  = (const float*)d_in[2];
  const float* Wq  = (const float*)d_in[3];
  const float* bq  = (const float*)d_in[4];
  const float* Wk  = (const float*)d_in[5];
  const float* bk  = (const float*)d_in[6];
  const float* Wv  = (const float*)d_in[7];
  const float* bv  = (const float*)d_in[8];
  const float* Wf  = (const float*)d_in[9];
  const float* bf  = (const float*)d_in[10];
  const float* Wo  = (const float*)d_in[11];
  const float* bo  = (const float*)d_in[12];
  const float* lng = (const float*)d_in[13];
  const float* lnb = (const float*)d_in[14];
  float* out = (float*)d_out;

  const size_t NQ = (size_t)B_ * N_ * HID_;  // 5,120,000

  char* base = (char*)d_ws;
  size_t off = 0;
  float* Q    = (float*)(base + off); off += NQ * 4;                 // 20.48MB
  float* agg  = (float*)(base + off); off += NQ * 4;                 // 20.48MB
  float* eas  = (float*)(base + off); off += (size_t)E_ * 16 * 4;    // 10.24MB
  unsigned char* kv8 = (unsigned char*)(base + off);
  off += (size_t)B_ * N_ * 256;                                      // 10.24MB
  unsigned char* film8 = (unsigned char*)(base + off);
  off += (size_t)E_ * 256;                                           // 40.96MB
  short* wt   = (short*)(base + off); off += 4 * 16384 * 2;          // 128KB
  int*  cnt    = (int*)(base + off); off += N_ * 4;
  int*  rowptr = (int*)(base + off); off += (N_ + 1) * 4;
  int*  fill   = (int*)(base + off); off += N_ * 4;
  int*  esrc   = (int*)(base + off); off += E_ * 4;

  hipMemsetAsync(cnt, 0, N_ * sizeof(int), stream);

  wt_prep<<<256, 256, 0, stream>>>(Wq, Wk, Wv, Wo, wt);
  qkv_mfma<<<(B_ * N_) / 16, 64, 0, stream>>>(x, wt, bq, bk, bv, Q, kv8);
  csr_hist<<<(E_ + 255) / 256, 256, 0, stream>>>(ei, cnt);
  csr_scan<<<1, 1024, 0, stream>>>(cnt, rowptr, fill);
  csr_scatter<<<(E_ + 255) / 256, 256, 0, stream>>>(ei, ea, fill, esrc, eas);
  film_prep<<<PGRID, 256, 0, stream>>>(eas, Wf, bf, film8);
  fused_attn<<<PGRID, 256, 0, stream>>>(rowptr, esrc, film8, Q, kv8, agg);
  out_ln_mfma<<<(B_ * N_) / 16, 64, 0, stream>>>(agg, wt + 3 * 16384, bo, x, lng, lnb, out);
}

// Round 17
// 171.224 us; speedup vs baseline: 1.3839x; 1.0233x over previous
//
#include <hip/hip_runtime.h>
#include <hip/hip_bf16.h>

#define B_ 4
#define N_ 10000
#define E_ 160000
#define D_ 128
#define H_ 4
#define HID_ 128
#define DK_ 32
#define DE_ 16
#define PGRID 2048

typedef __attribute__((ext_vector_type(8))) short short8v;
typedef __attribute__((ext_vector_type(4))) short short4v;
typedef __attribute__((ext_vector_type(4))) float f32x4;
typedef __attribute__((ext_vector_type(2))) float f32x2;

// fp32 -> bf16 bits, round-to-nearest-even
__device__ __forceinline__ short bfb(float f) {
  union { float f; unsigned u; } c; c.f = f;
  unsigned u = c.u + 0x7FFFu + ((c.u >> 16) & 1u);
  return (short)(u >> 16);
}
// bf16 bits -> fp32
__device__ __forceinline__ float b2f(unsigned short u) {
  union { unsigned u; float f; } c; c.u = ((unsigned)u) << 16;
  return c.f;
}

// fp32 -> fp8 e4m3 (OCP on gfx950)
__device__ __forceinline__ unsigned char f2fp8(float f) {
  int r = __builtin_amdgcn_cvt_pk_fp8_f32(f, f, 0, false);
  return (unsigned char)(r & 0xff);
}
// dword of 4 fp8 -> 2+2 fp32
__device__ __forceinline__ f32x2 fp8lo(unsigned u) {
  return __builtin_amdgcn_cvt_pk_f32_fp8((int)u, false);
}
__device__ __forceinline__ f32x2 fp8hi(unsigned u) {
  return __builtin_amdgcn_cvt_pk_f32_fp8((int)u, true);
}

// ---------------------------------------------------------------------------
// P0: W^T bf16 prep. wt[m][n][k] = bf16(W_m[k*128+n]),  m: 0=q 1=k 2=v 3=o
// ---------------------------------------------------------------------------
__global__ __launch_bounds__(256) void wt_prep(
    const float* __restrict__ Wq, const float* __restrict__ Wk,
    const float* __restrict__ Wv, const float* __restrict__ Wo,
    short* __restrict__ wt) {
  const float* Ws[4] = {Wq, Wk, Wv, Wo};
  const int i = blockIdx.x * 256 + threadIdx.x;   // 0..65535
  const int m = i >> 14;
  const int k = (i >> 7) & 127;
  const int n = i & 127;
  wt[(size_t)m * 16384 + n * 128 + k] = bfb(Ws[m][k * 128 + n]);
}

// ---------------------------------------------------------------------------
// K1: QKV projection via MFMA. ONE WAVE per block, 16 rows/block, grid 2500.
// Q -> bf16 [b][n][128]; K,V -> fp8 e4m3 kv8[n][b][0:128 = K | 128:256 = V]
// ---------------------------------------------------------------------------
__global__ __launch_bounds__(64) void qkv_mfma(
    const float* __restrict__ x, const short* __restrict__ wt,
    const float* __restrict__ bq, const float* __restrict__ bk,
    const float* __restrict__ bv,
    unsigned short* __restrict__ Qb, unsigned char* __restrict__ kv8) {
  __shared__ short xs[16][136];
  const int lane = threadIdx.x;
  const int ln15 = lane & 15;
  const int g    = lane >> 4;
  const long rowBase = (long)blockIdx.x * 16;

  for (int i = lane; i < 16 * 32; i += 64) {
    const int r  = i >> 5;
    const int c4 = (i & 31) * 4;
    const float4 v = *(const float4*)(x + (rowBase + r) * 128 + c4);
    short4v sv; sv.x = bfb(v.x); sv.y = bfb(v.y); sv.z = bfb(v.z); sv.w = bfb(v.w);
    *(short4v*)&xs[r][c4] = sv;
  }
  __syncthreads();

  short8v af[4];
#pragma unroll
  for (int kk = 0; kk < 4; ++kk)
    af[kk] = *(const short8v*)&xs[ln15][kk * 32 + g * 8];

  const float* bs[3] = {bq, bk, bv};

  int bbv[4], nnv[4];
#pragma unroll
  for (int r = 0; r < 4; ++r) {
    const long row = rowBase + g * 4 + r;
    bbv[r] = (int)(row / N_);
    nnv[r] = (int)(row - (long)bbv[r] * N_);
  }

#pragma unroll
  for (int m = 0; m < 3; ++m) {
    const short* Wt = wt + (size_t)m * 16384;
    f32x4 acc[8];
#pragma unroll
    for (int cb = 0; cb < 8; ++cb) acc[cb] = (f32x4){0.f, 0.f, 0.f, 0.f};

#pragma unroll
    for (int kk = 0; kk < 4; ++kk) {
#pragma unroll
      for (int cb = 0; cb < 8; ++cb) {
        const short8v bfr =
            *(const short8v*)(Wt + (cb * 16 + ln15) * 128 + kk * 32 + g * 8);
        acc[cb] = __builtin_amdgcn_mfma_f32_16x16x32_bf16(af[kk], bfr, acc[cb], 0, 0, 0);
      }
    }

    const float* bias = bs[m];
#pragma unroll
    for (int cb = 0; cb < 8; ++cb) {
      const int col = cb * 16 + ln15;
      const float bv_ = bias[col];
#pragma unroll
      for (int r = 0; r < 4; ++r) {
        const float val = acc[cb][r] + bv_;
        if (m == 0) {
          const long row = rowBase + g * 4 + r;
          Qb[row * 128 + col] = (unsigned short)bfb(val);
        } else {
          kv8[(((size_t)nnv[r] * 4 + bbv[r]) << 8) + (m - 1) * 128 + col] = f2fp8(val);
        }
      }
    }
  }
}

// ---------------------------------------------------------------------------
// CSR build
// ---------------------------------------------------------------------------
__global__ __launch_bounds__(256) void csr_hist(const int* __restrict__ ei,
                                                int* __restrict__ cnt) {
  const int e = blockIdx.x * 256 + threadIdx.x;
  if (e < E_) atomicAdd(&cnt[ei[E_ + e]], 1);
}

__global__ __launch_bounds__(1024) void csr_scan(const int* __restrict__ cnt,
                                                 int* __restrict__ rowptr,
                                                 int* __restrict__ fill) {
  __shared__ int part[1024];
  const int t = threadIdx.x;
  int local[10];
  int sum = 0;
#pragma unroll
  for (int i = 0; i < 10; ++i) {
    const int idx = t * 10 + i;
    local[i] = sum;
    sum += (idx < N_) ? cnt[idx] : 0;
  }
  part[t] = sum;
  __syncthreads();
  for (int off = 1; off < 1024; off <<= 1) {
    const int v = (t >= off) ? part[t - off] : 0;
    __syncthreads();
    part[t] += v;
    __syncthreads();
  }
  const int excl = (t == 0) ? 0 : part[t - 1];
#pragma unroll
  for (int i = 0; i < 10; ++i) {
    const int idx = t * 10 + i;
    if (idx <= N_) {
      const int o = excl + local[i];
      rowptr[idx] = o;
      if (idx < N_) fill[idx] = o;
    }
  }
}

// scatter: CSR-ordered src + inverse position map (no edge_attr copy)
__global__ __launch_bounds__(256) void csr_scatter(
    const int* __restrict__ ei, int* __restrict__ fill,
    int* __restrict__ esrc, int* __restrict__ epos) {
  const int e = blockIdx.x * 256 + threadIdx.x;
  if (e < E_) {
    const int dst = ei[E_ + e];
    const int pos = atomicAdd(&fill[dst], 1);
    esrc[pos] = ei[e];
    epos[e] = pos;
  }
}

// ---------------------------------------------------------------------------
// P1: FiLM precompute, fp8 RAW (gamma WITHOUT +1; beta raw).
// Reads ea in ORIGINAL edge order (streaming), writes film8 at CSR pos
// epos[e] (256B fully-written blocks). film8[pos][0:128]=gamma, [128:256]=beta.
// ---------------------------------------------------------------------------
__global__ __launch_bounds__(256) void film_prep(
    const float* __restrict__ ea, const int* __restrict__ epos,
    const float* __restrict__ Wf, const float* __restrict__ bf,
    unsigned char* __restrict__ film8) {
  const int lane = threadIdx.x & 63;
  const int wave = threadIdx.x >> 6;
  const int c0 = lane * 4;

  float4 w[16];
#pragma unroll
  for (int j = 0; j < 16; ++j) w[j] = *(const float4*)(Wf + j * 256 + c0);
  const float4 bias = *(const float4*)(bf + c0);

  for (int i = blockIdx.x * 4 + wave; i < E_; i += PGRID * 4) {
    const float* ep = ea + (size_t)i * 16;
    const float4 a0 = *(const float4*)ep;
    const float4 a1 = *(const float4*)(ep + 4);
    const float4 a2 = *(const float4*)(ep + 8);
    const float4 a3 = *(const float4*)(ep + 12);
    const float ev[16] = {a0.x,a0.y,a0.z,a0.w, a1.x,a1.y,a1.z,a1.w,
                          a2.x,a2.y,a2.z,a2.w, a3.x,a3.y,a3.z,a3.w};
    float ox = bias.x, oy = bias.y, oz = bias.z, ow = bias.w;
#pragma unroll
    for (int j = 0; j < 16; ++j) {
      ox = fmaf(ev[j], w[j].x, ox);
      oy = fmaf(ev[j], w[j].y, oy);
      oz = fmaf(ev[j], w[j].z, oz);
      ow = fmaf(ev[j], w[j].w, ow);
    }
    int r = __builtin_amdgcn_cvt_pk_fp8_f32(ox, oy, 0, false);
    r = __builtin_amdgcn_cvt_pk_fp8_f32(oz, ow, r, true);
    const int pos = epos[i];
    ((int*)(film8 + (size_t)pos * 256))[lane] = r;
  }
}

// ---------------------------------------------------------------------------
// K2: fused logits + softmax + aggregation — ZERO shuffles in the edge loop.
// Persistent: PGRID blocks x 4 waves; wave = node (grid-stride).
// lane = e2*32 + dh*16 + b*4 + h: lane owns 16 dims (half-head dh of head h,
// batch b) for edge-slot e2. q (bf16) and acc in registers; K/V/gamma/beta
// are single 16B fp8 loads. km = k + fma(k,g,t)  (g = raw gamma, t = beta).
// Logit: in-lane 16-dot + ONE shfl_xor(16) to join dh halves; exp per-lane.
// End of node: acc/se joined over e2 via shfl_xor(32); e2==0 lanes write.
// Single-pass softmax (no max): logits are O(0.05).
// ---------------------------------------------------------------------------
__global__ __launch_bounds__(256) void fused_attn(
    const int* __restrict__ rowptr, const int* __restrict__ esrc,
    const unsigned char* __restrict__ film8, const unsigned short* __restrict__ Qb,
    const unsigned char* __restrict__ kv8, float* __restrict__ agg) {
  const int wave = threadIdx.x >> 6;
  const int lane = threadIdx.x & 63;
  const int e2 = lane >> 5;
  const int dh = (lane >> 4) & 1;
  const int b  = (lane >> 2) & 3;
  const int h  = lane & 3;
  const int col0 = h * 32 + dh * 16;

  for (int node = blockIdx.x * 4 + wave; node < N_; node += PGRID * 4) {
    const int beg = rowptr[node], end = rowptr[node + 1];

    float q[16];
    {
      const unsigned short* qp = Qb + ((size_t)b * N_ + node) * 128 + col0;
      const short8v t0 = *(const short8v*)qp;
      const short8v t1 = *(const short8v*)(qp + 8);
#pragma unroll
      for (int j = 0; j < 8; ++j) {
        q[j]     = b2f((unsigned short)t0[j]);
        q[8 + j] = b2f((unsigned short)t1[j]);
      }
    }
    float acc[16];
#pragma unroll
    for (int d = 0; d < 16; ++d) acc[d] = 0.f;
    float se = 0.f;

    for (int i0 = beg; i0 < end; i0 += 2) {
      const int ii = i0 + e2;
      const bool valid = ii < end;
      const int ic = valid ? ii : i0;
      const int src = esrc[ic];
      const unsigned char* kp = kv8 + ((((size_t)src << 2) + b) << 8) + col0;
      const unsigned char* fp = film8 + (size_t)ic * 256 + col0;
      const uint4 kw = *(const uint4*)kp;
      const uint4 vw = *(const uint4*)(kp + 128);
      const uint4 gw = *(const uint4*)fp;
      const uint4 tw = *(const uint4*)(fp + 128);
      const unsigned ks[4] = {kw.x, kw.y, kw.z, kw.w};
      const unsigned vs[4] = {vw.x, vw.y, vw.z, vw.w};
      const unsigned gs[4] = {gw.x, gw.y, gw.z, gw.w};
      const unsigned ts[4] = {tw.x, tw.y, tw.z, tw.w};

      float pacc[4] = {0.f, 0.f, 0.f, 0.f};
#pragma unroll
      for (int w = 0; w < 4; ++w) {
        const f32x2 k0 = fp8lo(ks[w]), k1 = fp8hi(ks[w]);
        const f32x2 g0 = fp8lo(gs[w]), g1 = fp8hi(gs[w]);
        const f32x2 t0 = fp8lo(ts[w]), t1 = fp8hi(ts[w]);
        float km;
        km = k0.x + fmaf(k0.x, g0.x, t0.x); pacc[w] = fmaf(q[4*w+0], km, pacc[w]);
        km = k0.y + fmaf(k0.y, g0.y, t0.y); pacc[w] = fmaf(q[4*w+1], km, pacc[w]);
        km = k1.x + fmaf(k1.x, g1.x, t1.x); pacc[w] = fmaf(q[4*w+2], km, pacc[w]);
        km = k1.y + fmaf(k1.y, g1.y, t1.y); pacc[w] = fmaf(q[4*w+3], km, pacc[w]);
      }
      float pl = (pacc[0] + pacc[1]) + (pacc[2] + pacc[3]);
      pl += __shfl_xor(pl, 16);   // join dh halves -> full 32-dim logit

      float ex = __expf(pl * 0.17677669529663687f);  // 1/sqrt(32)
      ex = valid ? ex : 0.f;
      se += ex;
#pragma unroll
      for (int w = 0; w < 4; ++w) {
        const f32x2 v0 = fp8lo(vs[w]), v1 = fp8hi(vs[w]);
        acc[4*w+0] = fmaf(ex, v0.x, acc[4*w+0]);
        acc[4*w+1] = fmaf(ex, v0.y, acc[4*w+1]);
        acc[4*w+2] = fmaf(ex, v1.x, acc[4*w+2]);
        acc[4*w+3] = fmaf(ex, v1.y, acc[4*w+3]);
      }
    }

    // join the two e2 slots
#pragma unroll
    for (int d = 0; d < 16; ++d) acc[d] += __shfl_xor(acc[d], 32);
    se += __shfl_xor(se, 32);

    if (e2 == 0) {
      const float inv = (end > beg) ? 1.f / se : 0.f;
      float* ap = agg + ((size_t)b * N_ + node) * 128 + col0;
#pragma unroll
      for (int c = 0; c < 4; ++c) {
        float4 o;
        o.x = acc[c*4+0] * inv; o.y = acc[c*4+1] * inv;
        o.z = acc[c*4+2] * inv; o.w = acc[c*4+3] * inv;
        *(float4*)(ap + c * 4) = o;
      }
    }
  }
}

// ---------------------------------------------------------------------------
// K4: y = agg @ Wo + bo (MFMA); h = x + y; LayerNorm(h) -> out
// ONE WAVE per block, 16 rows/block, grid 2500.
// ---------------------------------------------------------------------------
__global__ __launch_bounds__(64) void out_ln_mfma(
    const float* __restrict__ agg, const short* __restrict__ wto,
    const float* __restrict__ bo, const float* __restrict__ x,
    const float* __restrict__ lng, const float* __restrict__ lnb,
    float* __restrict__ out) {
  __shared__ short as_[16][136];
  const int lane = threadIdx.x;
  const int ln15 = lane & 15;
  const int g    = lane >> 4;
  const long rowBase = (long)blockIdx.x * 16;

  for (int i = lane; i < 16 * 32; i += 64) {
    const int r  = i >> 5;
    const int c4 = (i & 31) * 4;
    const float4 v = *(const float4*)(agg + (rowBase + r) * 128 + c4);
    short4v sv; sv.x = bfb(v.x); sv.y = bfb(v.y); sv.z = bfb(v.z); sv.w = bfb(v.w);
    *(short4v*)&as_[r][c4] = sv;
  }
  __syncthreads();

  short8v af[4];
#pragma unroll
  for (int kk = 0; kk < 4; ++kk)
    af[kk] = *(const short8v*)&as_[ln15][kk * 32 + g * 8];

  f32x4 acc[8];
#pragma unroll
  for (int cb = 0; cb < 8; ++cb) acc[cb] = (f32x4){0.f, 0.f, 0.f, 0.f};

#pragma unroll
  for (int kk = 0; kk < 4; ++kk) {
#pragma unroll
    for (int cb = 0; cb < 8; ++cb) {
      const short8v bfr =
          *(const short8v*)(wto + (cb * 16 + ln15) * 128 + kk * 32 + g * 8);
      acc[cb] = __builtin_amdgcn_mfma_f32_16x16x32_bf16(af[kk], bfr, acc[cb], 0, 0, 0);
    }
  }

#pragma unroll
  for (int cb = 0; cb < 8; ++cb) {
    const int col = cb * 16 + ln15;
    const float bov = bo[col];
#pragma unroll
    for (int r = 0; r < 4; ++r) {
      const long row = rowBase + g * 4 + r;
      acc[cb][r] += bov + x[row * 128 + col];
    }
  }

  float s1[4], s2[4];
#pragma unroll
  for (int r = 0; r < 4; ++r) {
    s1[r] = 0.f; s2[r] = 0.f;
#pragma unroll
    for (int cb = 0; cb < 8; ++cb) {
      s1[r] += acc[cb][r];
      s2[r] = fmaf(acc[cb][r], acc[cb][r], s2[r]);
    }
  }
#pragma unroll
  for (int m = 1; m < 16; m <<= 1) {
#pragma unroll
    for (int r = 0; r < 4; ++r) {
      s1[r] += __shfl_xor(s1[r], m);
      s2[r] += __shfl_xor(s2[r], m);
    }
  }
  float mu[4], inv[4];
#pragma unroll
  for (int r = 0; r < 4; ++r) {
    mu[r] = s1[r] * (1.f / 128.f);
    const float var = s2[r] * (1.f / 128.f) - mu[r] * mu[r];
    inv[r] = rsqrtf(var + 1e-5f);
  }

#pragma unroll
  for (int cb = 0; cb < 8; ++cb) {
    const int col = cb * 16 + ln15;
    const float gv = lng[col], bv_ = lnb[col];
#pragma unroll
    for (int r = 0; r < 4; ++r) {
      const long row = rowBase + g * 4 + r;
      out[row * 128 + col] = (acc[cb][r] - mu[r]) * inv[r] * gv + bv_;
    }
  }
}

// ---------------------------------------------------------------------------
extern "C" void kernel_launch(void* const* d_in, const int* in_sizes, int n_in,
                              void* d_out, int out_size, void* d_ws, size_t ws_size,
                              hipStream_t stream) {
  const float* x   = (const float*)d_in[0];
  const int*   ei  = (const int*)d_in[1];
  const float* ea  = (const float*)d_in[2];
  const float* Wq  = (const float*)d_in[3];
  const float* bq  = (const float*)d_in[4];
  const float* Wk  = (const float*)d_in[5];
  const float* bk  = (const float*)d_in[6];
  const float* Wv  = (const float*)d_in[7];
  const float* bv  = (const float*)d_in[8];
  const float* Wf  = (const float*)d_in[9];
  const float* bf  = (const float*)d_in[10];
  const float* Wo  = (const float*)d_in[11];
  const float* bo  = (const float*)d_in[12];
  const float* lng = (const float*)d_in[13];
  const float* lnb = (const float*)d_in[14];
  float* out = (float*)d_out;

  const size_t NQ = (size_t)B_ * N_ * HID_;  // 5,120,000

  char* base = (char*)d_ws;
  size_t off = 0;
  unsigned short* Qb = (unsigned short*)(base + off); off += NQ * 2;   // 10.24MB
  float* agg  = (float*)(base + off); off += NQ * 4;                   // 20.48MB
  unsigned char* kv8 = (unsigned char*)(base + off);
  off += (size_t)B_ * N_ * 256;                                        // 10.24MB
  unsigned char* film8 = (unsigned char*)(base + off);
  off += (size_t)E_ * 256;                                             // 40.96MB
  short* wt   = (short*)(base + off); off += 4 * 16384 * 2;            // 128KB
  int*  cnt    = (int*)(base + off); off += N_ * 4;
  int*  rowptr = (int*)(base + off); off += (N_ + 1) * 4;
  int*  fill   = (int*)(base + off); off += N_ * 4;
  int*  esrc   = (int*)(base + off); off += E_ * 4;
  int*  epos   = (int*)(base + off); off += E_ * 4;

  hipMemsetAsync(cnt, 0, N_ * sizeof(int), stream);

  wt_prep<<<256, 256, 0, stream>>>(Wq, Wk, Wv, Wo, wt);
  qkv_mfma<<<(B_ * N_) / 16, 64, 0, stream>>>(x, wt, bq, bk, bv, Qb, kv8);
  csr_hist<<<(E_ + 255) / 256, 256, 0, stream>>>(ei, cnt);
  csr_scan<<<1, 1024, 0, stream>>>(cnt, rowptr, fill);
  csr_scatter<<<(E_ + 255) / 256, 256, 0, stream>>>(ei, fill, esrc, epos);
  film_prep<<<PGRID, 256, 0, stream>>>(ea, epos, Wf, bf, film8);
  fused_attn<<<PGRID, 256, 0, stream>>>(rowptr, esrc, film8, Qb, kv8, agg);
  out_ln_mfma<<<(B_ * N_) / 16, 64, 0, stream>>>(agg, wt + 3 * 16384, bo, x, lng, lnb, out);
}